// Round 9
// baseline (928.063 us; speedup 1.0000x reference)
//
#include <hip/hip_runtime.h>
#include <hip/hip_bf16.h>

// ---------------- workspace layout v18 (total 74,842,112 bytes) ----------------
// float indices into (float*)d_ws:
#define FC0_F   0        // fc0_w [64][3]
#define FC0B_F  192      // fc0_b [64]
#define PWB_F   16640    // pw_b [4][64]
#define FC1B_F  25088    // fc1_b [128]
#define FC2_F   25216    // fc2_w [128]
#define FC2B_F  25344    // fc2_b [1]
#define PHW_F   25408    // phW [256 w][12 ky][2] f32 (unused by kernels now; kept for layout)
#define PHH_F   31552    // phH [256 x][24 kx][2] f32 (spec + layer inv-H DFT)
#define FLAG_F  44032    // 1.0 => inputs f32
// u16 (bf16) element indices into (unsigned short*)d_ws:
#define PWA_HI_U 512     // pw [4][64 o][64 c] bf16 hi  (bytes 1024..33791)
#define PWA_LO_U 16896   // pw lo                       (bytes 33792..66559)
#define FC1A_HI_U 33792  // fc1 [128 f][64 c] bf16 hi (old f32 FC1T region)
#define FC1A_LO_U 41984  // fc1 lo (ends 50175 < 50176 = FC1B_F in u16)
#define TWI_HI_U 88192   // inv-W twiddle [256 w][32 k] hi (bytes 176384..192767)
#define TWI_LO_U 96384   // inv-W lo                       (bytes 192768..209151)
#define TWF_HI_U 104576  // fwd-W twiddle [32 r][256 w] hi (bytes 209152..225535)
#define TWF_LO_U 112768  // fwd-W lo                       (bytes 225536..241919)
// bf16 element indices into (__hip_bfloat16*)d_ws:
#define HB_OFF_U  131072     // h [8][256][256][64]  (33554432 elems)
#define GG_OFF_U  33685504   // G region: [8][256] rows x 1536 bf16
// float index for Fo:
#define FO_OFF_F  18415616   // Fo [8][12][24][64][2] f32 (294912)
#define WS_NEED   74842112
#define NT11 60161           // table items: same count as v12-v17

typedef short bf16x8 __attribute__((ext_vector_type(8)));   // 8 bf16 (4 VGPRs)
typedef float f32x4  __attribute__((ext_vector_type(4)));

union FU10 { float f; unsigned u; };
__device__ __forceinline__ float bfu2f(unsigned short u) { FU10 v; v.u = ((unsigned)u) << 16; return v.f; }
__device__ __forceinline__ unsigned short f2bfu(float f) {
  FU10 v; v.f = f; unsigned b = v.u;
  return (unsigned short)((b + 0x7FFFu + ((b >> 16) & 1u)) >> 16);   // RNE
}
__device__ __forceinline__ unsigned pk2bf(float a, float b) {
  return (unsigned)f2bfu(a) | ((unsigned)f2bfu(b) << 16);
}
// Branchless GELU: Abramowitz-Stegun 7.1.26 erf (max err 1.5e-7) + native rcp/exp.
__device__ __forceinline__ float gelu10(float v) {
  float s = v * 0.7071067811865475f;
  float a = fabsf(s);
  float t = __builtin_amdgcn_rcpf(1.0f + 0.3275911f * a);
  float p = t*(0.254829592f + t*(-0.284496736f + t*(1.421413741f
          + t*(-1.453152027f + t*1.061405429f))));
  float er = 1.0f - p * __expf(-a * a);
  er = copysignf(er, s);
  return 0.5f * v * (1.0f + er);
}
__device__ __forceinline__ float rdw10(const __hip_bfloat16* h, const float* f,
                                       long i, int isf32) {
  return isf32 ? f[i] : __bfloat162float(h[i]);
}
// g2T XOR swizzle: row o (64B rows), byte-in-row br; bijective, 16B-chunk aligned.
__device__ __forceinline__ int gsw17(int o, int br) {
  return (o*64 + br) ^ ((o & 7) << 4);
}

// ---------------- fill output with a code (guards only) ----------------
__global__ __launch_bounds__(256) void kf10_fill(__hip_bfloat16* outH, float code) {
  outH[(size_t)blockIdx.x * 256 + threadIdx.x] = __float2bfloat16(code);
}

// ---------------- dtype detect on X ----------------
__global__ __launch_bounds__(64) void kd10_detect(const unsigned short* Xh, float* Wf) {
  if (threadIdx.x == 0 && blockIdx.x == 0) {
    int ok = 1;
    for (int k = 0; k < 128; ++k) {
      unsigned short u = Xh[2 * k];
      unsigned e = (u >> 7) & 0xFF;
      if (!(u == 0 || (e >= 0x60 && e <= 0x88))) ok = 0;
    }
    Wf[FLAG_F] = ok ? 0.0f : 1.0f;
  }
}

// ---------------- tables ----------------
__global__ __launch_bounds__(256) void kt10_tables(
    const __hip_bfloat16* f0h, const float* f0f,
    const __hip_bfloat16* f0bh, const float* f0bf,
    const __hip_bfloat16* pwh, const float* pwf,
    const __hip_bfloat16* pwbh, const float* pwbf,
    const __hip_bfloat16* f1h, const float* f1f,
    const __hip_bfloat16* f1bh, const float* f1bf,
    const __hip_bfloat16* f2h, const float* f2f,
    const __hip_bfloat16* f2bh, const float* f2bf,
    float* Wf) {
  unsigned short* Wu = (unsigned short*)Wf;
  const int isf32 = (Wf[FLAG_F] != 0.0f);
  const int stride = gridDim.x * blockDim.x;
  for (int n0 = blockIdx.x * blockDim.x + threadIdx.x; n0 < NT11; n0 += stride) {
    int n = n0;
    if (n < 192) { Wf[FC0_F + n] = rdw10(f0h, f0f, n, isf32); continue; }
    n -= 192;
    if (n < 64)  { Wf[FC0B_F + n] = rdw10(f0bh, f0bf, n, isf32); continue; }
    n -= 64;
    if (n < 256) { Wf[PWB_F + n] = rdw10(pwbh, pwbf, n, isf32); continue; }
    n -= 256;
    if (n < 8192) {             // fc1 split bf16, natural [f][c] layout
      float v = rdw10(f1h, f1f, n, isf32);
      unsigned short hi = f2bfu(v);
      Wu[FC1A_HI_U + n] = hi;
      Wu[FC1A_LO_U + n] = f2bfu(v - bfu2f(hi));
      continue;
    }
    n -= 8192;
    if (n < 128) { Wf[FC1B_F + n] = rdw10(f1bh, f1bf, n, isf32); continue; }
    n -= 128;
    if (n < 128) { Wf[FC2_F + n] = rdw10(f2h, f2f, n, isf32); continue; }
    n -= 128;
    if (n < 1)   { Wf[FC2B_F + n] = rdw10(f2bh, f2bf, 0, isf32); continue; }
    n -= 1;
    if (n < 6144) { int w = n / 24, r = n % 24, ky = r >> 1, part = r & 1;
      int idx = (w * ky) & 255; float a = idx * (1.0f/128.0f);
      Wf[PHW_F + n] = part ? sinpif(a) : cospif(a); continue; }
    n -= 6144;
    if (n < 12288) { int xx = n / 48, r = n % 48, kx = r >> 1, part = r & 1;
      int kxa = (kx < 12) ? kx : kx + 232;          // 244..255 = negative H rows
      int idx = (xx * kxa) & 255; float a = idx * (1.0f/128.0f);
      Wf[PHH_F + n] = part ? sinpif(a) : cospif(a); continue; }
    n -= 12288;
    if (n < 16384) {            // pw split bf16, [l][o][c] == input linear layout
      float v = rdw10(pwh, pwf, n, isf32);
      unsigned short hi = f2bfu(v);
      Wu[PWA_HI_U + n] = hi;
      Wu[PWA_LO_U + n] = f2bfu(v - bfu2f(hi));
      continue;
    }
    n -= 16384;
    if (n < 8192) {             // inv-W twiddle [256 w][32 k], scale 1/65536 folded in
      int w = n >> 5, k = n & 31;
      float v;
      if (k == 0)      v = 1.0f / 65536.0f;
      else if (k < 12) { int idx = (w*k) & 255;
        v =  2.0f * cospif(idx * (1.0f/128.0f)) * (1.0f/65536.0f); }
      else if (k < 23) { int ky = k - 11; int idx = (w*ky) & 255;
        v = -2.0f * sinpif(idx * (1.0f/128.0f)) * (1.0f/65536.0f); }
      else v = 0.0f;
      unsigned short hi = f2bfu(v);
      Wu[TWI_HI_U + n] = hi;
      Wu[TWI_LO_U + n] = f2bfu(v - bfu2f(hi));
      continue;
    }
    n -= 8192;
    {                           // fwd-W twiddle [32 r][256 w]: r<12 cos, 12..23 -sin, rest 0
      int r = n >> 8, w = n & 255;
      float v;
      if (r < 12)      { int idx = (w*r) & 255;  v =  cospif(idx * (1.0f/128.0f)); }
      else if (r < 24) { int ky = r - 12; int idx = (w*ky) & 255;
                         v = -sinpif(idx * (1.0f/128.0f)); }
      else v = 0.0f;
      unsigned short hi = f2bfu(v);
      Wu[TWF_HI_U + n] = hi;
      Wu[TWF_LO_U + n] = f2bfu(v - bfu2f(hi));
    }
  }
}

// ---------------- lift v18: fc0 in registers -> HB + swizzled LDS image ->
//                  MFMA fwd DFT-W -> GG (unchanged) ------------------------------
__global__ __launch_bounds__(256) void kl11_lift(const __hip_bfloat16* Xh, const float* Xf,
                                                 const float* Wf,
                                                 __hip_bfloat16* HB, __hip_bfloat16* GG) {
  __shared__ __align__(16) char smem[32768];
  unsigned short* gbT = (unsigned short*)smem;   // phase-2 staging (aliases image)
  const unsigned short* Wu = (const unsigned short*)Wf;
  const int rid = ((blockIdx.x & 7) << 8) | (blockIdx.x >> 3);
  const int b = rid >> 8, x = rid & 255;
  const int t = threadIdx.x;
  const int w = t;                               // this thread's pixel
  const int l15 = t & 15, g = (t >> 4) & 3, wv = t >> 6;
  const int isf32 = (Wf[FLAG_F] != 0.0f);
  float xv = isf32 ? Xf[(size_t)(b*256 + x)*256 + w]
                   : __bfloat162float(Xh[(size_t)(b*256 + x)*256 + w]);
  float gx = x * (1.0f/255.0f), gy = w * (1.0f/255.0f);
  unsigned hbreg[32];
#pragma unroll
  for (int cp = 0; cp < 32; ++cp) {
    int c = cp*2;
    float h0 = xv*Wf[FC0_F + c*3]     + gx*Wf[FC0_F + c*3 + 1]
             + gy*Wf[FC0_F + c*3 + 2] + Wf[FC0B_F + c];
    float h1 = xv*Wf[FC0_F + c*3 + 3] + gx*Wf[FC0_F + c*3 + 4]
             + gy*Wf[FC0_F + c*3 + 5] + Wf[FC0B_F + c + 1];
    unsigned pk = pk2bf(h0, h1);
    hbreg[cp] = pk;
    // channel-major swizzled image for the MFMA fwd-DFT A-side
    *(unsigned short*)(smem + (((c+0)*512 + w*2) ^ (((c+0) & 7) << 4))) =
        (unsigned short)(pk & 0xFFFFu);
    *(unsigned short*)(smem + (((c+1)*512 + w*2) ^ (((c+1) & 7) << 4))) =
        (unsigned short)(pk >> 16);
  }
  // HB store: this lane fully covers its own 128 B pixel line
  {
    uint4* hbW = (uint4*)(HB + (size_t)(b*256 + x)*16384) + w*8;
#pragma unroll
    for (int j = 0; j < 8; ++j)
      hbW[j] = make_uint4(hbreg[j*4], hbreg[j*4+1], hbreg[j*4+2], hbreg[j*4+3]);
  }
  __syncthreads();                               // image complete

  // ---- MFMA fwd DFT-W: G[c][r] = sum_w h[w][c] * TwFwd[r][w] ----
  f32x4 g0 = {0.f, 0.f, 0.f, 0.f}, g1 = {0.f, 0.f, 0.f, 0.f};
  const int crow = wv*16 + l15;                  // A row (channel)
  const int rswz = (crow & 7) << 4;
#pragma unroll
  for (int kk = 0; kk < 8; ++kk) {
    const int k0 = kk*32;
    bf16x8 af  = *(const bf16x8*)(smem + ((crow*512 + (k0 + g*8)*2) ^ rswz));
    bf16x8 b0h = *(const bf16x8*)(Wu + TWF_HI_U + l15*256 + k0 + g*8);
    bf16x8 b0l = *(const bf16x8*)(Wu + TWF_LO_U + l15*256 + k0 + g*8);
    bf16x8 b1h = *(const bf16x8*)(Wu + TWF_HI_U + (16 + l15)*256 + k0 + g*8);
    bf16x8 b1l = *(const bf16x8*)(Wu + TWF_LO_U + (16 + l15)*256 + k0 + g*8);
    g0 = __builtin_amdgcn_mfma_f32_16x16x32_bf16(af, b0h, g0, 0, 0, 0);
    g0 = __builtin_amdgcn_mfma_f32_16x16x32_bf16(af, b0l, g0, 0, 0, 0);
    g1 = __builtin_amdgcn_mfma_f32_16x16x32_bf16(af, b1h, g1, 0, 0, 0);
    g1 = __builtin_amdgcn_mfma_f32_16x16x32_bf16(af, b1l, g1, 0, 0, 0);
  }
  __syncthreads();                               // image reads done; staging may overwrite
#pragma unroll
  for (int ntk = 0; ntk < 2; ++ntk) {
    int kyt = ntk*16 + l15;                      // C col = ky term
    if (kyt < 24) {
      f32x4 gg = ntk ? g1 : g0;
#pragma unroll
      for (int rr = 0; rr < 4; ++rr)
        gbT[(wv*16 + g*4 + rr)*24 + kyt] = f2bfu(gg[rr]);
    }
  }
  __syncthreads();                               // staging complete
  unsigned* GGrow = (unsigned*)((unsigned short*)GG + (size_t)(b*256 + x)*1536);
  const unsigned* st32 = (const unsigned*)gbT;
#pragma unroll
  for (int j = 0; j < 3; ++j) GGrow[j*256 + t] = st32[j*256 + t];
}

// ---------------- spectral v18: 256-thread (round-6 A/B winner) -----------------
// Block=(b,kx), XCD swizzle b = blockIdx&7.
__global__ __launch_bounds__(256) void ks12_spec(const float* Wf, const __hip_bfloat16* GG,
    const __hip_bfloat16* w1h, const float* w1f,
    const __hip_bfloat16* w2h, const float* w2f,
    float* Fo, int l) {
  __shared__ float pbufA[6400];
  __shared__ float Fbuf[1536];     // F [i][24]: m<12 re[ky], m>=12 im[ky]
  const int blk = (blockIdx.x & 7) * 24 + (blockIdx.x >> 3);
  const int b = blk / 24, kx = blk % 24;
  const int t = threadIdx.x;
  const int isf32 = (Wf[FLAG_F] != 0.0f);
  // A: F[i][ky] = sum_x G[b][x][i][ky] * e^{-i 2pi x kxa/256}
  {
    const int i = t & 63, q = t >> 6;
    float fr[12], fi[12];
#pragma unroll
    for (int k = 0; k < 12; ++k) { fr[k] = 0.0f; fi[k] = 0.0f; }
    for (int j = 0; j < 64; ++j) {
      int x = q*64 + j;                          // wave-uniform
      const uint4* gp = (const uint4*)((const unsigned short*)GG
                        + (size_t)(b*256 + x)*1536 + i*24);
      uint4 u0 = gp[0], u1 = gp[1], u2 = gp[2];
      float cc = Wf[PHH_F + x*48 + 2*kx], sn = Wf[PHH_F + x*48 + 2*kx + 1];
      unsigned uu[12] = {u0.x, u0.y, u0.z, u0.w, u1.x, u1.y, u1.z, u1.w,
                         u2.x, u2.y, u2.z, u2.w};
      // G layout: elems 0..11 = re[k], 12..23 = im[k]
#pragma unroll
      for (int k = 0; k < 12; ++k) {
        unsigned ure = uu[k >> 1], uim = uu[6 + (k >> 1)];
        float gr = bfu2f((unsigned short)((k & 1) ? (ure >> 16) : (ure & 0xFFFFu)));
        float gi = bfu2f((unsigned short)((k & 1) ? (uim >> 16) : (uim & 0xFFFFu)));
        fr[k] += gr*cc + gi*sn;
        fi[k] += gi*cc - gr*sn;
      }
    }
#pragma unroll
    for (int k = 0; k < 12; ++k) {
      pbufA[q*1600 + i*25 + 2*k]     = fr[k];
      pbufA[q*1600 + i*25 + 2*k + 1] = fi[k];
    }
  }
  __syncthreads();
#pragma unroll
  for (int j = 0; j < 6; ++j) {
    int idx = j*256 + t;                         // 1536 = i*24 + m
    int cc = idx / 24, m = idx - cc*24;
    Fbuf[idx] = pbufA[cc*25 + m] + pbufA[1600 + cc*25 + m]
              + pbufA[3200 + cc*25 + m] + pbufA[4800 + cc*25 + m];
  }
  __syncthreads();
  // B: Fo[ky][o] = sum_i F[i][ky] * W[l][i][o][kx][ky]
  {
    const int o = t & 63, q = t >> 6;
    float br[12], bi[12];
#pragma unroll
    for (int k = 0; k < 12; ++k) { br[k] = 0.0f; bi[k] = 0.0f; }
    const int kxe = (kx < 12) ? kx : kx - 12;
    const __hip_bfloat16* wh = (kx < 12) ? w1h : w2h;
    const float*         wfp = (kx < 12) ? w1f : w2f;
    for (int i = q*16; i < q*16 + 16; ++i) {
      size_t widx = ((size_t)((l*64 + i)*64 + o))*288 + (size_t)kxe*24;
      float wr_[12], wi_[12];
      if (isf32) {
        const float* wp = wfp + widx;
#pragma unroll
        for (int k = 0; k < 12; ++k) { wr_[k] = wp[2*k]; wi_[k] = wp[2*k + 1]; }
      } else {
        const uint4* wp = (const uint4*)((const unsigned short*)wh + widx);
        uint4 u0 = wp[0], u1 = wp[1], u2 = wp[2];
        unsigned uu[12] = {u0.x, u0.y, u0.z, u0.w, u1.x, u1.y, u1.z, u1.w,
                           u2.x, u2.y, u2.z, u2.w};
#pragma unroll
        for (int k = 0; k < 12; ++k) {
          wr_[k] = bfu2f((unsigned short)(uu[k] & 0xFFFFu));
          wi_[k] = bfu2f((unsigned short)(uu[k] >> 16));
        }
      }
      const float* Fp = Fbuf + i*24;
#pragma unroll
      for (int k = 0; k < 12; ++k) {
        float Fr = Fp[k], Fi = Fp[12 + k];
        br[k] += Fr*wr_[k] - Fi*wi_[k];
        bi[k] += Fr*wi_[k] + Fi*wr_[k];
      }
    }
#pragma unroll
    for (int k = 0; k < 12; ++k) {
      pbufA[q*1536 + k*128 + o*2]     = br[k];
      pbufA[q*1536 + k*128 + o*2 + 1] = bi[k];
    }
  }
  __syncthreads();
#pragma unroll
  for (int j = 0; j < 6; ++j) {
    int n = j*256 + t;                           // 1536 = ky*128 + o*2 + p
    int ky = n >> 7, r = n & 127;
    Fo[((size_t)(b*12 + ky)*24 + kx)*128 + r] =
        pbufA[n] + pbufA[1536 + n] + pbufA[3072 + n] + pbufA[4608 + n];
  }
}

// ---------------- layer v18: 5 blocks/CU target; fragments loaded per-iter -------
// Block = one (b,x) row (XCD-chunked). 32 KB LDS (5 blocks = 160 KB exactly).
// __launch_bounds__(256,5): VGPR cap ~102. Phase-1 restructured mt-outer/nt-inner
// with unroll 1 and per-iter apw/bi loads (L2-hot tables) to fit the cap without
// spills. Per-tile math identical to v17 -> bit-identical output.
__global__ __launch_bounds__(256, 5) void ky14_layer(const float* __restrict__ Wf,
                                                     __hip_bfloat16* __restrict__ HB,
                                                     __hip_bfloat16* __restrict__ GG,
                                                     const float* __restrict__ Fo,
                                                     __hip_bfloat16* __restrict__ outH,
                                                     float* __restrict__ outF,
                                                     int l, int last) {
  __shared__ __align__(16) char smem[32768];
  unsigned short* gbT = (unsigned short*)smem;   // staging [64][24] for phase 2 only
  const unsigned short* Wu = (const unsigned short*)Wf;
  const int rid = ((blockIdx.x & 7) << 8) | (blockIdx.x >> 3);
  const int b = rid >> 8, x = rid & 255;
  const int t = threadIdx.x;
  const int l15 = t & 15, g = (t >> 4) & 3, wv = t >> 6;

  unsigned short* HBu = (unsigned short*)(HB + (size_t)(b*256 + x)*16384);
  unsigned short* GGu = (unsigned short*)GG + (size_t)(b*256 + x)*1536;

  // ---- issue h_old global loads first (longest latency) ----
  const int w0w = wv*64;                     // wave owns pixels [w0w, w0w+64)
  bf16x8 bh[4][2];                           // pointwise B: h_old frags from HB global
#pragma unroll
  for (int nt = 0; nt < 4; ++nt) {
    int wpx = w0w + nt*16 + l15;
#pragma unroll
    for (int kt = 0; kt < 2; ++kt)
      bh[nt][kt] = *(const bf16x8*)(HBu + (size_t)wpx*64 + kt*32 + g*8);
  }

  // ---- phase 0: inline inverse-H DFT: Fo -> g2T (XOR-swizzled) in LDS ----
  { int o = t >> 2, cu = t & 3;              // zero cols 24-31 (bytes 48..63 of row)
    *(unsigned*)(smem + gsw17(o, 48 + cu*4)) = 0u; }
  {
    const float* phx = Wf + PHH_F + x*48;    // block-uniform twiddles
#pragma unroll 1
    for (int j = 0; j < 3; ++j) {
      int p = j*256 + t; int ky = p >> 6, o = p & 63;
      const float2* Fop = (const float2*)(Fo + (size_t)(b*12 + ky)*3072) + o;
      float gr = 0.0f, gi = 0.0f;
#pragma unroll
      for (int kx = 0; kx < 24; ++kx) {
        float2 f = Fop[kx*64];
        float cc = phx[2*kx], sn = phx[2*kx + 1];
        gr += f.x*cc - f.y*sn;
        gi += f.x*sn + f.y*cc;
      }
      *(unsigned short*)(smem + gsw17(o, ky*2)) = f2bfu(gr);             // re -> col ky
      *(unsigned short*)(smem + gsw17(o, (ky ? (11 + ky) : 23)*2)) = f2bfu(gi);
    }
  }

  __syncthreads();                           // g2T complete
  bf16x8 ainv[4];                            // inv-DFT A: g2T frags (swizzled read)
#pragma unroll
  for (int mt = 0; mt < 4; ++mt)
    ainv[mt] = *(const bf16x8*)(smem + gsw17(mt*16 + l15, g*16));
  __syncthreads();                           // frag reads done; image may overwrite

  // ---- phase 1: 16 C-tiles per wave (mt-outer); per-iter weight loads ----
  // !last: image is [c][w] (channel-major) for the fwd-DFT A-side.
  //  last: image is [w][c] (pixel-major)   for the head's B-side; HB write skipped.
#pragma unroll 1
  for (int mt = 0; mt < 4; ++mt) {
    const int c0 = mt*16 + g*4;              // C rows = channels c0..c0+3
    bf16x8 apw0h, apw0l, apw1h, apw1l;
    {
      int off = l*4096 + (mt*16 + l15)*64 + g*8;
      apw0h = *(const bf16x8*)(Wu + PWA_HI_U + off);
      apw0l = *(const bf16x8*)(Wu + PWA_LO_U + off);
      apw1h = *(const bf16x8*)(Wu + PWA_HI_U + off + 32);
      apw1l = *(const bf16x8*)(Wu + PWA_LO_U + off + 32);
    }
    float bias0 = Wf[PWB_F + l*64 + c0];
    float bias1 = Wf[PWB_F + l*64 + c0 + 1];
    float bias2 = Wf[PWB_F + l*64 + c0 + 2];
    float bias3 = Wf[PWB_F + l*64 + c0 + 3];
#pragma unroll 1
    for (int nt = 0; nt < 4; ++nt) {
      const int wpx = w0w + nt*16 + l15;     // C col (pixel) for this lane
      bf16x8 bi0 = *(const bf16x8*)(Wu + TWI_HI_U + wpx*32 + g*8);
      bf16x8 bi1 = *(const bf16x8*)(Wu + TWI_LO_U + wpx*32 + g*8);
      f32x4 acc = {bias0, bias1, bias2, bias3};
      acc = __builtin_amdgcn_mfma_f32_16x16x32_bf16(ainv[mt], bi0,       acc, 0, 0, 0);
      acc = __builtin_amdgcn_mfma_f32_16x16x32_bf16(ainv[mt], bi1,       acc, 0, 0, 0);
      acc = __builtin_amdgcn_mfma_f32_16x16x32_bf16(apw0h,    bh[nt][0], acc, 0, 0, 0);
      acc = __builtin_amdgcn_mfma_f32_16x16x32_bf16(apw0l,    bh[nt][0], acc, 0, 0, 0);
      acc = __builtin_amdgcn_mfma_f32_16x16x32_bf16(apw1h,    bh[nt][1], acc, 0, 0, 0);
      acc = __builtin_amdgcn_mfma_f32_16x16x32_bf16(apw1l,    bh[nt][1], acc, 0, 0, 0);
      float v0 = acc[0], v1 = acc[1], v2 = acc[2], v3 = acc[3];
      if (!last) { v0 = gelu10(v0); v1 = gelu10(v1); v2 = gelu10(v2); v3 = gelu10(v3); }
      uint2 pk; pk.x = pk2bf(v0, v1); pk.y = pk2bf(v2, v3);
      if (!last) {
        *(uint2*)(HBu + (size_t)wpx*64 + c0) = pk;
        // h_new^T image for fwd-DFT, XOR-swizzled
        *(unsigned short*)(smem + (((c0+0)*512 + wpx*2) ^ (((c0+0) & 7) << 4))) = f2bfu(v0);
        *(unsigned short*)(smem + (((c0+1)*512 + wpx*2) ^ (((c0+1) & 7) << 4))) = f2bfu(v1);
        *(unsigned short*)(smem + (((c0+2)*512 + wpx*2) ^ (((c0+2) & 7) << 4))) = f2bfu(v2);
        *(unsigned short*)(smem + (((c0+3)*512 + wpx*2) ^ (((c0+3) & 7) << 4))) = f2bfu(v3);
      } else {
        // pixel-major h image for head B-frags, XOR-swizzled on pixel
        *(uint2*)(smem + ((wpx*128 + c0*2) ^ ((wpx & 7) << 4))) = pk;
      }
    }
  }

  if (!last) {
    // ---- phase 2: fwd DFT-W: G[c][r] = sum_w h_new[w][c] * TwFwd[r][w] ----
    __syncthreads();                         // h_new image complete
    f32x4 g0 = {0.f, 0.f, 0.f, 0.f}, g1 = {0.f, 0.f, 0.f, 0.f};
    const int crow = wv*16 + l15;            // A row (channel); wave owns c-slab wv*16..+16
    const int rswz = (crow & 7) << 4;
#pragma unroll
    for (int kk = 0; kk < 8; ++kk) {
      const int k0 = kk*32;
      bf16x8 af  = *(const bf16x8*)(smem + ((crow*512 + (k0 + g*8)*2) ^ rswz));
      bf16x8 b0h = *(const bf16x8*)(Wu + TWF_HI_U + l15*256 + k0 + g*8);
      bf16x8 b0l = *(const bf16x8*)(Wu + TWF_LO_U + l15*256 + k0 + g*8);
      bf16x8 b1h = *(const bf16x8*)(Wu + TWF_HI_U + (16 + l15)*256 + k0 + g*8);
      bf16x8 b1l = *(const bf16x8*)(Wu + TWF_LO_U + (16 + l15)*256 + k0 + g*8);
      g0 = __builtin_amdgcn_mfma_f32_16x16x32_bf16(af, b0h, g0, 0, 0, 0);
      g0 = __builtin_amdgcn_mfma_f32_16x16x32_bf16(af, b0l, g0, 0, 0, 0);
      g1 = __builtin_amdgcn_mfma_f32_16x16x32_bf16(af, b1h, g1, 0, 0, 0);
      g1 = __builtin_amdgcn_mfma_f32_16x16x32_bf16(af, b1l, g1, 0, 0, 0);
    }
    __syncthreads();                         // image reads done; staging may overwrite
    // stage [64 c][24 r] bf16 into gbT (linear layout), then coalesced GG store
#pragma unroll
    for (int ntk = 0; ntk < 2; ++ntk) {
      int kyt = ntk*16 + l15;                // C col = kyterm
      if (kyt < 24) {
        f32x4 gg = ntk ? g1 : g0;
#pragma unroll
        for (int rr = 0; rr < 4; ++rr)
          gbT[(wv*16 + g*4 + rr)*24 + kyt] = f2bfu(gg[rr]);
      }
    }
    __syncthreads();                         // staging complete
    unsigned* GGrow = (unsigned*)GGu;
    const unsigned* st32 = (const unsigned*)gbT;
#pragma unroll
    for (int j = 0; j < 3; ++j) GGrow[j*256 + t] = st32[j*256 + t];
  } else {
    // ---- phase 2': fused head: fc1 (hi/lo MFMA) + GELU + fc2 reduce -> out ----
    __syncthreads();                         // h image complete
    const int isf32 = (Wf[FLAG_F] != 0.0f);
    bf16x8 bh2[4][2];                        // B frags from the swizzled LDS image
#pragma unroll
    for (int nt = 0; nt < 4; ++nt) {
      int wpx = w0w + nt*16 + l15;
#pragma unroll
      for (int kt = 0; kt < 2; ++kt)
        bh2[nt][kt] = *(const bf16x8*)(smem +
            ((wpx*128 + kt*64 + g*16) ^ ((wpx & 7) << 4)));
    }
    float s[4] = {0.0f, 0.0f, 0.0f, 0.0f};
#pragma unroll 1
    for (int mt = 0; mt < 8; ++mt) {
      const int arow = (mt*16 + l15)*64 + g*8;
      bf16x8 a0h = *(const bf16x8*)(Wu + FC1A_HI_U + arow);
      bf16x8 a0l = *(const bf16x8*)(Wu + FC1A_LO_U + arow);
      bf16x8 a1h = *(const bf16x8*)(Wu + FC1A_HI_U + arow + 32);
      bf16x8 a1l = *(const bf16x8*)(Wu + FC1A_LO_U + arow + 32);
      float f1b[4], f2v[4];
#pragma unroll
      for (int r = 0; r < 4; ++r) {
        f1b[r] = Wf[FC1B_F + mt*16 + g*4 + r];
        f2v[r] = Wf[FC2_F  + mt*16 + g*4 + r];
      }
#pragma unroll
      for (int nt = 0; nt < 4; ++nt) {
        f32x4 acc = {f1b[0], f1b[1], f1b[2], f1b[3]};
        acc = __builtin_amdgcn_mfma_f32_16x16x32_bf16(a0h, bh2[nt][0], acc, 0, 0, 0);
        acc = __builtin_amdgcn_mfma_f32_16x16x32_bf16(a0l, bh2[nt][0], acc, 0, 0, 0);
        acc = __builtin_amdgcn_mfma_f32_16x16x32_bf16(a1h, bh2[nt][1], acc, 0, 0, 0);
        acc = __builtin_amdgcn_mfma_f32_16x16x32_bf16(a1l, bh2[nt][1], acc, 0, 0, 0);
#pragma unroll
        for (int r = 0; r < 4; ++r)
          s[nt] += gelu10(acc[r]) * f2v[r];
      }
    }
    const float fc2b = Wf[FC2B_F];
#pragma unroll
    for (int nt = 0; nt < 4; ++nt) {
      float v = s[nt];
      v += __shfl_xor(v, 16);
      v += __shfl_xor(v, 32);
      if (g == 0) {
        size_t idx = (size_t)(b*256 + x)*256 + (w0w + nt*16 + l15);
        if (isf32) outF[idx] = v + fc2b;
        else       outH[idx] = __float2bfloat16(v + fc2b);
      }
    }
  }
}

// ---------------- launcher ----------------
extern "C" void kernel_launch(void* const* d_in, const int* in_sizes, int n_in,
                              void* d_out, int out_size, void* d_ws, size_t ws_size,
                              hipStream_t stream) {
  (void)out_size;
  __hip_bfloat16* outH = (__hip_bfloat16*)d_out;
  float*          outF = (float*)d_out;
  float*          Wf   = (float*)d_ws;
  __hip_bfloat16* HB   = (__hip_bfloat16*)d_ws + HB_OFF_U;
  __hip_bfloat16* GG   = (__hip_bfloat16*)d_ws + GG_OFF_U;
  float*          Fo   = (float*)d_ws + FO_OFF_F;

  static const int EXP_SZ[11] = {524288, 192, 64, 4718592, 4718592,
                                 16384, 256, 8192, 128, 128, 1};
  if (n_in != 11) { kf10_fill<<<2048, 256, 0, stream>>>(outH, 27648.0f); return; }
  for (int i = 0; i < 11; ++i) {
    if (in_sizes[i] != EXP_SZ[i]) {
      kf10_fill<<<2048, 256, 0, stream>>>(outH, 28672.0f + 256.0f * (float)i);
      return;
    }
  }
  if (ws_size < (size_t)WS_NEED) {
    int q = (int)(ws_size >> 25); if (q > 31) q = 31;
    kf10_fill<<<2048, 256, 0, stream>>>(outH, 4096.0f + 32.0f * (float)q);
    return;
  }

  kd10_detect<<<1, 64, 0, stream>>>((const unsigned short*)d_in[0], Wf);
  kt10_tables<<<64, 256, 0, stream>>>(
      (const __hip_bfloat16*)d_in[1], (const float*)d_in[1],
      (const __hip_bfloat16*)d_in[2], (const float*)d_in[2],
      (const __hip_bfloat16*)d_in[5], (const float*)d_in[5],
      (const __hip_bfloat16*)d_in[6], (const float*)d_in[6],
      (const __hip_bfloat16*)d_in[7], (const float*)d_in[7],
      (const __hip_bfloat16*)d_in[8], (const float*)d_in[8],
      (const __hip_bfloat16*)d_in[9], (const float*)d_in[9],
      (const __hip_bfloat16*)d_in[10], (const float*)d_in[10],
      Wf);
  kl11_lift<<<2048, 256, 0, stream>>>((const __hip_bfloat16*)d_in[0],
                                      (const float*)d_in[0], Wf, HB, GG);
  for (int l = 0; l < 4; ++l) {
    ks12_spec<<<192, 256, 0, stream>>>(Wf, GG,
        (const __hip_bfloat16*)d_in[3], (const float*)d_in[3],
        (const __hip_bfloat16*)d_in[4], (const float*)d_in[4],
        Fo, l);
    ky14_layer<<<2048, 256, 0, stream>>>(Wf, HB, GG, Fo, outH, outF,
                                         l, (l == 3) ? 1 : 0);
  }
}

// Round 10
// 690.085 us; speedup vs baseline: 1.3449x; 1.3449x over previous
//
#include <hip/hip_runtime.h>
#include <hip/hip_bf16.h>

// ---------------- workspace layout v19 (total 74,842,112 bytes) ----------------
// float indices into (float*)d_ws:
#define FC0_F   0        // fc0_w [64][3]
#define FC0B_F  192      // fc0_b [64]
#define PWB_F   16640    // pw_b [4][64]
#define FC1B_F  25088    // fc1_b [128]
#define FC2_F   25216    // fc2_w [128]
#define FC2B_F  25344    // fc2_b [1]
#define PHW_F   25408    // phW [256 w][12 ky][2] f32 (unused by kernels now; kept for layout)
#define PHH_F   31552    // phH [256 x][24 kx][2] f32 (spec + layer inv-H DFT)
#define FLAG_F  44032    // 1.0 => inputs f32
// u16 (bf16) element indices into (unsigned short*)d_ws:
#define PWA_HI_U 512     // pw [4][64 o][64 c] bf16 hi  (bytes 1024..33791)
#define PWA_LO_U 16896   // pw lo                       (bytes 33792..66559)
#define FC1A_HI_U 33792  // fc1 [128 f][64 c] bf16 hi (old f32 FC1T region)
#define FC1A_LO_U 41984  // fc1 lo (ends 50175 < 50176 = FC1B_F in u16)
#define TWI_HI_U 88192   // inv-W twiddle [256 w][32 k] hi (bytes 176384..192767)
#define TWI_LO_U 96384   // inv-W lo                       (bytes 192768..209151)
#define TWF_HI_U 104576  // fwd-W twiddle [32 r][256 w] hi (bytes 209152..225535)
#define TWF_LO_U 112768  // fwd-W lo                       (bytes 225536..241919)
// bf16 element indices into (__hip_bfloat16*)d_ws:
#define HB_OFF_U  131072     // h [8][256][256][64]  (33554432 elems)
#define GG_OFF_U  33685504   // G region: [8][256] rows x 1536 bf16
// float index for Fo:
#define FO_OFF_F  18415616   // Fo [8][12][24][64][2] f32 (294912)
#define WS_NEED   74842112
#define NT11 60161           // table items: same count as v12-v18

typedef short bf16x8 __attribute__((ext_vector_type(8)));   // 8 bf16 (4 VGPRs)
typedef float f32x4  __attribute__((ext_vector_type(4)));

union FU10 { float f; unsigned u; };
__device__ __forceinline__ float bfu2f(unsigned short u) { FU10 v; v.u = ((unsigned)u) << 16; return v.f; }
__device__ __forceinline__ unsigned short f2bfu(float f) {
  FU10 v; v.f = f; unsigned b = v.u;
  return (unsigned short)((b + 0x7FFFu + ((b >> 16) & 1u)) >> 16);   // RNE
}
__device__ __forceinline__ unsigned pk2bf(float a, float b) {
  return (unsigned)f2bfu(a) | ((unsigned)f2bfu(b) << 16);
}
// Branchless GELU: Abramowitz-Stegun 7.1.26 erf (max err 1.5e-7) + native rcp/exp.
__device__ __forceinline__ float gelu10(float v) {
  float s = v * 0.7071067811865475f;
  float a = fabsf(s);
  float t = __builtin_amdgcn_rcpf(1.0f + 0.3275911f * a);
  float p = t*(0.254829592f + t*(-0.284496736f + t*(1.421413741f
          + t*(-1.453152027f + t*1.061405429f))));
  float er = 1.0f - p * __expf(-a * a);
  er = copysignf(er, s);
  return 0.5f * v * (1.0f + er);
}
__device__ __forceinline__ float rdw10(const __hip_bfloat16* h, const float* f,
                                       long i, int isf32) {
  return isf32 ? f[i] : __bfloat162float(h[i]);
}
// g2T XOR swizzle: row o (64B rows), byte-in-row br; bijective, 16B-chunk aligned.
__device__ __forceinline__ int gsw17(int o, int br) {
  return (o*64 + br) ^ ((o & 7) << 4);
}

// ---------------- fill output with a code (guards only) ----------------
__global__ __launch_bounds__(256) void kf10_fill(__hip_bfloat16* outH, float code) {
  outH[(size_t)blockIdx.x * 256 + threadIdx.x] = __float2bfloat16(code);
}

// ---------------- dtype detect on X ----------------
__global__ __launch_bounds__(64) void kd10_detect(const unsigned short* Xh, float* Wf) {
  if (threadIdx.x == 0 && blockIdx.x == 0) {
    int ok = 1;
    for (int k = 0; k < 128; ++k) {
      unsigned short u = Xh[2 * k];
      unsigned e = (u >> 7) & 0xFF;
      if (!(u == 0 || (e >= 0x60 && e <= 0x88))) ok = 0;
    }
    Wf[FLAG_F] = ok ? 0.0f : 1.0f;
  }
}

// ---------------- tables ----------------
__global__ __launch_bounds__(256) void kt10_tables(
    const __hip_bfloat16* f0h, const float* f0f,
    const __hip_bfloat16* f0bh, const float* f0bf,
    const __hip_bfloat16* pwh, const float* pwf,
    const __hip_bfloat16* pwbh, const float* pwbf,
    const __hip_bfloat16* f1h, const float* f1f,
    const __hip_bfloat16* f1bh, const float* f1bf,
    const __hip_bfloat16* f2h, const float* f2f,
    const __hip_bfloat16* f2bh, const float* f2bf,
    float* Wf) {
  unsigned short* Wu = (unsigned short*)Wf;
  const int isf32 = (Wf[FLAG_F] != 0.0f);
  const int stride = gridDim.x * blockDim.x;
  for (int n0 = blockIdx.x * blockDim.x + threadIdx.x; n0 < NT11; n0 += stride) {
    int n = n0;
    if (n < 192) { Wf[FC0_F + n] = rdw10(f0h, f0f, n, isf32); continue; }
    n -= 192;
    if (n < 64)  { Wf[FC0B_F + n] = rdw10(f0bh, f0bf, n, isf32); continue; }
    n -= 64;
    if (n < 256) { Wf[PWB_F + n] = rdw10(pwbh, pwbf, n, isf32); continue; }
    n -= 256;
    if (n < 8192) {             // fc1 split bf16, natural [f][c] layout
      float v = rdw10(f1h, f1f, n, isf32);
      unsigned short hi = f2bfu(v);
      Wu[FC1A_HI_U + n] = hi;
      Wu[FC1A_LO_U + n] = f2bfu(v - bfu2f(hi));
      continue;
    }
    n -= 8192;
    if (n < 128) { Wf[FC1B_F + n] = rdw10(f1bh, f1bf, n, isf32); continue; }
    n -= 128;
    if (n < 128) { Wf[FC2_F + n] = rdw10(f2h, f2f, n, isf32); continue; }
    n -= 128;
    if (n < 1)   { Wf[FC2B_F + n] = rdw10(f2bh, f2bf, 0, isf32); continue; }
    n -= 1;
    if (n < 6144) { int w = n / 24, r = n % 24, ky = r >> 1, part = r & 1;
      int idx = (w * ky) & 255; float a = idx * (1.0f/128.0f);
      Wf[PHW_F + n] = part ? sinpif(a) : cospif(a); continue; }
    n -= 6144;
    if (n < 12288) { int xx = n / 48, r = n % 48, kx = r >> 1, part = r & 1;
      int kxa = (kx < 12) ? kx : kx + 232;          // 244..255 = negative H rows
      int idx = (xx * kxa) & 255; float a = idx * (1.0f/128.0f);
      Wf[PHH_F + n] = part ? sinpif(a) : cospif(a); continue; }
    n -= 12288;
    if (n < 16384) {            // pw split bf16, [l][o][c] == input linear layout
      float v = rdw10(pwh, pwf, n, isf32);
      unsigned short hi = f2bfu(v);
      Wu[PWA_HI_U + n] = hi;
      Wu[PWA_LO_U + n] = f2bfu(v - bfu2f(hi));
      continue;
    }
    n -= 16384;
    if (n < 8192) {             // inv-W twiddle [256 w][32 k], scale 1/65536 folded in
      int w = n >> 5, k = n & 31;
      float v;
      if (k == 0)      v = 1.0f / 65536.0f;
      else if (k < 12) { int idx = (w*k) & 255;
        v =  2.0f * cospif(idx * (1.0f/128.0f)) * (1.0f/65536.0f); }
      else if (k < 23) { int ky = k - 11; int idx = (w*ky) & 255;
        v = -2.0f * sinpif(idx * (1.0f/128.0f)) * (1.0f/65536.0f); }
      else v = 0.0f;
      unsigned short hi = f2bfu(v);
      Wu[TWI_HI_U + n] = hi;
      Wu[TWI_LO_U + n] = f2bfu(v - bfu2f(hi));
      continue;
    }
    n -= 8192;
    {                           // fwd-W twiddle [32 r][256 w]: r<12 cos, 12..23 -sin, rest 0
      int r = n >> 8, w = n & 255;
      float v;
      if (r < 12)      { int idx = (w*r) & 255;  v =  cospif(idx * (1.0f/128.0f)); }
      else if (r < 24) { int ky = r - 12; int idx = (w*ky) & 255;
                         v = -sinpif(idx * (1.0f/128.0f)); }
      else v = 0.0f;
      unsigned short hi = f2bfu(v);
      Wu[TWF_HI_U + n] = hi;
      Wu[TWF_LO_U + n] = f2bfu(v - bfu2f(hi));
    }
  }
}

// ---------------- lift: fc0 in registers -> HB + swizzled LDS image ->
//                  MFMA fwd DFT-W -> GG ------------------------------------------
__global__ __launch_bounds__(256) void kl11_lift(const __hip_bfloat16* Xh, const float* Xf,
                                                 const float* Wf,
                                                 __hip_bfloat16* HB, __hip_bfloat16* GG) {
  __shared__ __align__(16) char smem[32768];
  unsigned short* gbT = (unsigned short*)smem;   // phase-2 staging (aliases image)
  const unsigned short* Wu = (const unsigned short*)Wf;
  const int rid = ((blockIdx.x & 7) << 8) | (blockIdx.x >> 3);
  const int b = rid >> 8, x = rid & 255;
  const int t = threadIdx.x;
  const int w = t;                               // this thread's pixel
  const int l15 = t & 15, g = (t >> 4) & 3, wv = t >> 6;
  const int isf32 = (Wf[FLAG_F] != 0.0f);
  float xv = isf32 ? Xf[(size_t)(b*256 + x)*256 + w]
                   : __bfloat162float(Xh[(size_t)(b*256 + x)*256 + w]);
  float gx = x * (1.0f/255.0f), gy = w * (1.0f/255.0f);
  unsigned hbreg[32];
#pragma unroll
  for (int cp = 0; cp < 32; ++cp) {
    int c = cp*2;
    float h0 = xv*Wf[FC0_F + c*3]     + gx*Wf[FC0_F + c*3 + 1]
             + gy*Wf[FC0_F + c*3 + 2] + Wf[FC0B_F + c];
    float h1 = xv*Wf[FC0_F + c*3 + 3] + gx*Wf[FC0_F + c*3 + 4]
             + gy*Wf[FC0_F + c*3 + 5] + Wf[FC0B_F + c + 1];
    unsigned pk = pk2bf(h0, h1);
    hbreg[cp] = pk;
    // channel-major swizzled image for the MFMA fwd-DFT A-side
    *(unsigned short*)(smem + (((c+0)*512 + w*2) ^ (((c+0) & 7) << 4))) =
        (unsigned short)(pk & 0xFFFFu);
    *(unsigned short*)(smem + (((c+1)*512 + w*2) ^ (((c+1) & 7) << 4))) =
        (unsigned short)(pk >> 16);
  }
  // HB store: this lane fully covers its own 128 B pixel line
  {
    uint4* hbW = (uint4*)(HB + (size_t)(b*256 + x)*16384) + w*8;
#pragma unroll
    for (int j = 0; j < 8; ++j)
      hbW[j] = make_uint4(hbreg[j*4], hbreg[j*4+1], hbreg[j*4+2], hbreg[j*4+3]);
  }
  __syncthreads();                               // image complete

  // ---- MFMA fwd DFT-W: G[c][r] = sum_w h[w][c] * TwFwd[r][w] ----
  f32x4 g0 = {0.f, 0.f, 0.f, 0.f}, g1 = {0.f, 0.f, 0.f, 0.f};
  const int crow = wv*16 + l15;                  // A row (channel)
  const int rswz = (crow & 7) << 4;
#pragma unroll
  for (int kk = 0; kk < 8; ++kk) {
    const int k0 = kk*32;
    bf16x8 af  = *(const bf16x8*)(smem + ((crow*512 + (k0 + g*8)*2) ^ rswz));
    bf16x8 b0h = *(const bf16x8*)(Wu + TWF_HI_U + l15*256 + k0 + g*8);
    bf16x8 b0l = *(const bf16x8*)(Wu + TWF_LO_U + l15*256 + k0 + g*8);
    bf16x8 b1h = *(const bf16x8*)(Wu + TWF_HI_U + (16 + l15)*256 + k0 + g*8);
    bf16x8 b1l = *(const bf16x8*)(Wu + TWF_LO_U + (16 + l15)*256 + k0 + g*8);
    g0 = __builtin_amdgcn_mfma_f32_16x16x32_bf16(af, b0h, g0, 0, 0, 0);
    g0 = __builtin_amdgcn_mfma_f32_16x16x32_bf16(af, b0l, g0, 0, 0, 0);
    g1 = __builtin_amdgcn_mfma_f32_16x16x32_bf16(af, b1h, g1, 0, 0, 0);
    g1 = __builtin_amdgcn_mfma_f32_16x16x32_bf16(af, b1l, g1, 0, 0, 0);
  }
  __syncthreads();                               // image reads done; staging may overwrite
#pragma unroll
  for (int ntk = 0; ntk < 2; ++ntk) {
    int kyt = ntk*16 + l15;                      // C col = ky term
    if (kyt < 24) {
      f32x4 gg = ntk ? g1 : g0;
#pragma unroll
      for (int rr = 0; rr < 4; ++rr)
        gbT[(wv*16 + g*4 + rr)*24 + kyt] = f2bfu(gg[rr]);
    }
  }
  __syncthreads();                               // staging complete
  unsigned* GGrow = (unsigned*)((unsigned short*)GG + (size_t)(b*256 + x)*1536);
  const unsigned* st32 = (const unsigned*)gbT;
#pragma unroll
  for (int j = 0; j < 3; ++j) GGrow[j*256 + t] = st32[j*256 + t];
}

// ---------------- spectral: 256-thread (round-6 A/B winner) ---------------------
// Block=(b,kx), XCD swizzle b = blockIdx&7.
__global__ __launch_bounds__(256) void ks12_spec(const float* Wf, const __hip_bfloat16* GG,
    const __hip_bfloat16* w1h, const float* w1f,
    const __hip_bfloat16* w2h, const float* w2f,
    float* Fo, int l) {
  __shared__ float pbufA[6400];
  __shared__ float Fbuf[1536];     // F [i][24]: m<12 re[ky], m>=12 im[ky]
  const int blk = (blockIdx.x & 7) * 24 + (blockIdx.x >> 3);
  const int b = blk / 24, kx = blk % 24;
  const int t = threadIdx.x;
  const int isf32 = (Wf[FLAG_F] != 0.0f);
  // A: F[i][ky] = sum_x G[b][x][i][ky] * e^{-i 2pi x kxa/256}
  {
    const int i = t & 63, q = t >> 6;
    float fr[12], fi[12];
#pragma unroll
    for (int k = 0; k < 12; ++k) { fr[k] = 0.0f; fi[k] = 0.0f; }
    for (int j = 0; j < 64; ++j) {
      int x = q*64 + j;                          // wave-uniform
      const uint4* gp = (const uint4*)((const unsigned short*)GG
                        + (size_t)(b*256 + x)*1536 + i*24);
      uint4 u0 = gp[0], u1 = gp[1], u2 = gp[2];
      float cc = Wf[PHH_F + x*48 + 2*kx], sn = Wf[PHH_F + x*48 + 2*kx + 1];
      unsigned uu[12] = {u0.x, u0.y, u0.z, u0.w, u1.x, u1.y, u1.z, u1.w,
                         u2.x, u2.y, u2.z, u2.w};
      // G layout: elems 0..11 = re[k], 12..23 = im[k]
#pragma unroll
      for (int k = 0; k < 12; ++k) {
        unsigned ure = uu[k >> 1], uim = uu[6 + (k >> 1)];
        float gr = bfu2f((unsigned short)((k & 1) ? (ure >> 16) : (ure & 0xFFFFu)));
        float gi = bfu2f((unsigned short)((k & 1) ? (uim >> 16) : (uim & 0xFFFFu)));
        fr[k] += gr*cc + gi*sn;
        fi[k] += gi*cc - gr*sn;
      }
    }
#pragma unroll
    for (int k = 0; k < 12; ++k) {
      pbufA[q*1600 + i*25 + 2*k]     = fr[k];
      pbufA[q*1600 + i*25 + 2*k + 1] = fi[k];
    }
  }
  __syncthreads();
#pragma unroll
  for (int j = 0; j < 6; ++j) {
    int idx = j*256 + t;                         // 1536 = i*24 + m
    int cc = idx / 24, m = idx - cc*24;
    Fbuf[idx] = pbufA[cc*25 + m] + pbufA[1600 + cc*25 + m]
              + pbufA[3200 + cc*25 + m] + pbufA[4800 + cc*25 + m];
  }
  __syncthreads();
  // B: Fo[ky][o] = sum_i F[i][ky] * W[l][i][o][kx][ky]
  {
    const int o = t & 63, q = t >> 6;
    float br[12], bi[12];
#pragma unroll
    for (int k = 0; k < 12; ++k) { br[k] = 0.0f; bi[k] = 0.0f; }
    const int kxe = (kx < 12) ? kx : kx - 12;
    const __hip_bfloat16* wh = (kx < 12) ? w1h : w2h;
    const float*         wfp = (kx < 12) ? w1f : w2f;
    for (int i = q*16; i < q*16 + 16; ++i) {
      size_t widx = ((size_t)((l*64 + i)*64 + o))*288 + (size_t)kxe*24;
      float wr_[12], wi_[12];
      if (isf32) {
        const float* wp = wfp + widx;
#pragma unroll
        for (int k = 0; k < 12; ++k) { wr_[k] = wp[2*k]; wi_[k] = wp[2*k + 1]; }
      } else {
        const uint4* wp = (const uint4*)((const unsigned short*)wh + widx);
        uint4 u0 = wp[0], u1 = wp[1], u2 = wp[2];
        unsigned uu[12] = {u0.x, u0.y, u0.z, u0.w, u1.x, u1.y, u1.z, u1.w,
                           u2.x, u2.y, u2.z, u2.w};
#pragma unroll
        for (int k = 0; k < 12; ++k) {
          wr_[k] = bfu2f((unsigned short)(uu[k] & 0xFFFFu));
          wi_[k] = bfu2f((unsigned short)(uu[k] >> 16));
        }
      }
      const float* Fp = Fbuf + i*24;
#pragma unroll
      for (int k = 0; k < 12; ++k) {
        float Fr = Fp[k], Fi = Fp[12 + k];
        br[k] += Fr*wr_[k] - Fi*wi_[k];
        bi[k] += Fr*wi_[k] + Fi*wr_[k];
      }
    }
#pragma unroll
    for (int k = 0; k < 12; ++k) {
      pbufA[q*1536 + k*128 + o*2]     = br[k];
      pbufA[q*1536 + k*128 + o*2 + 1] = bi[k];
    }
  }
  __syncthreads();
#pragma unroll
  for (int j = 0; j < 6; ++j) {
    int n = j*256 + t;                           // 1536 = ky*128 + o*2 + p
    int ky = n >> 7, r = n & 127;
    Fo[((size_t)(b*12 + ky)*24 + kx)*128 + r] =
        pbufA[n] + pbufA[1536 + n] + pbufA[3072 + n] + pbufA[4608 + n];
  }
}

// ---------------- layer v19 (= round-8 ky13): inline inv-H + MFMA inv-W DFT +
//                  pointwise (+GELU) + fwd-W DFT; last=1 fuses the head.
//                  g2T XOR-swizzled (gsw17). NO min-waves bound (spill hazard:
//                  round-9's (256,5) -> 48 VGPR, 200MB scratch, dur +50%). -------
__global__ __launch_bounds__(256) void ky13_layer(const float* __restrict__ Wf,
                                                  __hip_bfloat16* __restrict__ HB,
                                                  __hip_bfloat16* __restrict__ GG,
                                                  const float* __restrict__ Fo,
                                                  __hip_bfloat16* __restrict__ outH,
                                                  float* __restrict__ outF,
                                                  int l, int last) {
  __shared__ __align__(16) char smem[32768];
  unsigned short* gbT = (unsigned short*)smem;   // staging [64][24] for phase 2 only
  const unsigned short* Wu = (const unsigned short*)Wf;
  const int rid = ((blockIdx.x & 7) << 8) | (blockIdx.x >> 3);
  const int b = rid >> 8, x = rid & 255;
  const int t = threadIdx.x;
  const int l15 = t & 15, g = (t >> 4) & 3, wv = t >> 6;

  unsigned short* HBu = (unsigned short*)(HB + (size_t)(b*256 + x)*16384);
  unsigned short* GGu = (unsigned short*)GG + (size_t)(b*256 + x)*1536;

  // ---- issue h_old global loads first (longest latency) ----
  const int w0w = wv*64;                     // wave owns pixels [w0w, w0w+64)
  bf16x8 bh[4][2];                           // pointwise B: h_old frags from HB global
#pragma unroll
  for (int nt = 0; nt < 4; ++nt) {
    int wpx = w0w + nt*16 + l15;
#pragma unroll
    for (int kt = 0; kt < 2; ++kt)
      bh[nt][kt] = *(const bf16x8*)(HBu + (size_t)wpx*64 + kt*32 + g*8);
  }

  // ---- phase 0: inline inverse-H DFT: Fo -> g2T (XOR-swizzled) in LDS ----
  { int o = t >> 2, cu = t & 3;              // zero cols 24-31 (bytes 48..63 of row)
    *(unsigned*)(smem + gsw17(o, 48 + cu*4)) = 0u; }
  {
    const float* phx = Wf + PHH_F + x*48;    // block-uniform twiddles
#pragma unroll 1
    for (int j = 0; j < 3; ++j) {
      int p = j*256 + t; int ky = p >> 6, o = p & 63;
      const float2* Fop = (const float2*)(Fo + (size_t)(b*12 + ky)*3072) + o;
      float gr = 0.0f, gi = 0.0f;
#pragma unroll
      for (int kx = 0; kx < 24; ++kx) {
        float2 f = Fop[kx*64];
        float cc = phx[2*kx], sn = phx[2*kx + 1];
        gr += f.x*cc - f.y*sn;
        gi += f.x*sn + f.y*cc;
      }
      *(unsigned short*)(smem + gsw17(o, ky*2)) = f2bfu(gr);             // re -> col ky
      *(unsigned short*)(smem + gsw17(o, (ky ? (11 + ky) : 23)*2)) = f2bfu(gi);
    }
  }

  // ---- weight fragment loads (L2-hot) ----
  bf16x8 bi[4][2];                           // inv-DFT B: twiddle hi/lo
#pragma unroll
  for (int nt = 0; nt < 4; ++nt) {
    int wpx = w0w + nt*16 + l15;
    bi[nt][0] = *(const bf16x8*)(Wu + TWI_HI_U + wpx*32 + g*8);
    bi[nt][1] = *(const bf16x8*)(Wu + TWI_LO_U + wpx*32 + g*8);
  }
  bf16x8 apw[4][2][2];                       // pointwise A: pw[o][c] hi/lo
#pragma unroll
  for (int mt = 0; mt < 4; ++mt)
#pragma unroll
    for (int kt = 0; kt < 2; ++kt) {
      int off = l*4096 + (mt*16 + l15)*64 + kt*32 + g*8;
      apw[mt][kt][0] = *(const bf16x8*)(Wu + PWA_HI_U + off);
      apw[mt][kt][1] = *(const bf16x8*)(Wu + PWA_LO_U + off);
    }
  float bias[4][4];
#pragma unroll
  for (int mt = 0; mt < 4; ++mt)
#pragma unroll
    for (int r = 0; r < 4; ++r)
      bias[mt][r] = Wf[PWB_F + l*64 + mt*16 + g*4 + r];

  __syncthreads();                           // g2T complete
  bf16x8 ainv[4];                            // inv-DFT A: g2T frags (swizzled read)
#pragma unroll
  for (int mt = 0; mt < 4; ++mt)
    ainv[mt] = *(const bf16x8*)(smem + gsw17(mt*16 + l15, g*16));
  __syncthreads();                           // frag reads done; image may overwrite

  // ---- phase 1: 16 C-tiles per wave; epilogue -> HB + swizzled LDS image ----
  // !last: image is [c][w] (channel-major) for the fwd-DFT A-side.
  //  last: image is [w][c] (pixel-major)   for the head's B-side; HB write skipped.
#pragma unroll
  for (int nt = 0; nt < 4; ++nt) {
    const int wpx = w0w + nt*16 + l15;       // C col (pixel) for this lane
#pragma unroll
    for (int mt = 0; mt < 4; ++mt) {
      f32x4 acc = {bias[mt][0], bias[mt][1], bias[mt][2], bias[mt][3]};
      acc = __builtin_amdgcn_mfma_f32_16x16x32_bf16(ainv[mt],      bi[nt][0], acc, 0, 0, 0);
      acc = __builtin_amdgcn_mfma_f32_16x16x32_bf16(ainv[mt],      bi[nt][1], acc, 0, 0, 0);
      acc = __builtin_amdgcn_mfma_f32_16x16x32_bf16(apw[mt][0][0], bh[nt][0], acc, 0, 0, 0);
      acc = __builtin_amdgcn_mfma_f32_16x16x32_bf16(apw[mt][0][1], bh[nt][0], acc, 0, 0, 0);
      acc = __builtin_amdgcn_mfma_f32_16x16x32_bf16(apw[mt][1][0], bh[nt][1], acc, 0, 0, 0);
      acc = __builtin_amdgcn_mfma_f32_16x16x32_bf16(apw[mt][1][1], bh[nt][1], acc, 0, 0, 0);
      float v0 = acc[0], v1 = acc[1], v2 = acc[2], v3 = acc[3];
      if (!last) { v0 = gelu10(v0); v1 = gelu10(v1); v2 = gelu10(v2); v3 = gelu10(v3); }
      const int c0 = mt*16 + g*4;            // C rows = channels c0..c0+3
      uint2 pk; pk.x = pk2bf(v0, v1); pk.y = pk2bf(v2, v3);
      if (!last) {
        *(uint2*)(HBu + (size_t)wpx*64 + c0) = pk;
        // h_new^T image for fwd-DFT, XOR-swizzled
        *(unsigned short*)(smem + (((c0+0)*512 + wpx*2) ^ (((c0+0) & 7) << 4))) = f2bfu(v0);
        *(unsigned short*)(smem + (((c0+1)*512 + wpx*2) ^ (((c0+1) & 7) << 4))) = f2bfu(v1);
        *(unsigned short*)(smem + (((c0+2)*512 + wpx*2) ^ (((c0+2) & 7) << 4))) = f2bfu(v2);
        *(unsigned short*)(smem + (((c0+3)*512 + wpx*2) ^ (((c0+3) & 7) << 4))) = f2bfu(v3);
      } else {
        // pixel-major h image for head B-frags, XOR-swizzled on pixel
        *(uint2*)(smem + ((wpx*128 + c0*2) ^ ((wpx & 7) << 4))) = pk;
      }
    }
  }

  if (!last) {
    // ---- phase 2: fwd DFT-W: G[c][r] = sum_w h_new[w][c] * TwFwd[r][w] ----
    __syncthreads();                         // h_new image complete
    f32x4 g0 = {0.f, 0.f, 0.f, 0.f}, g1 = {0.f, 0.f, 0.f, 0.f};
    const int crow = wv*16 + l15;            // A row (channel); wave owns c-slab wv*16..+16
    const int rswz = (crow & 7) << 4;
#pragma unroll
    for (int kk = 0; kk < 8; ++kk) {
      const int k0 = kk*32;
      bf16x8 af  = *(const bf16x8*)(smem + ((crow*512 + (k0 + g*8)*2) ^ rswz));
      bf16x8 b0h = *(const bf16x8*)(Wu + TWF_HI_U + l15*256 + k0 + g*8);
      bf16x8 b0l = *(const bf16x8*)(Wu + TWF_LO_U + l15*256 + k0 + g*8);
      bf16x8 b1h = *(const bf16x8*)(Wu + TWF_HI_U + (16 + l15)*256 + k0 + g*8);
      bf16x8 b1l = *(const bf16x8*)(Wu + TWF_LO_U + (16 + l15)*256 + k0 + g*8);
      g0 = __builtin_amdgcn_mfma_f32_16x16x32_bf16(af, b0h, g0, 0, 0, 0);
      g0 = __builtin_amdgcn_mfma_f32_16x16x32_bf16(af, b0l, g0, 0, 0, 0);
      g1 = __builtin_amdgcn_mfma_f32_16x16x32_bf16(af, b1h, g1, 0, 0, 0);
      g1 = __builtin_amdgcn_mfma_f32_16x16x32_bf16(af, b1l, g1, 0, 0, 0);
    }
    __syncthreads();                         // image reads done; staging may overwrite
    // stage [64 c][24 r] bf16 into gbT (linear layout), then coalesced GG store
#pragma unroll
    for (int ntk = 0; ntk < 2; ++ntk) {
      int kyt = ntk*16 + l15;                // C col = kyterm
      if (kyt < 24) {
        f32x4 gg = ntk ? g1 : g0;
#pragma unroll
        for (int rr = 0; rr < 4; ++rr)
          gbT[(wv*16 + g*4 + rr)*24 + kyt] = f2bfu(gg[rr]);
      }
    }
    __syncthreads();                         // staging complete
    unsigned* GGrow = (unsigned*)GGu;
    const unsigned* st32 = (const unsigned*)gbT;
#pragma unroll
    for (int j = 0; j < 3; ++j) GGrow[j*256 + t] = st32[j*256 + t];
  } else {
    // ---- phase 2': fused head: fc1 (hi/lo MFMA) + GELU + fc2 reduce -> out ----
    __syncthreads();                         // h image complete
    const int isf32 = (Wf[FLAG_F] != 0.0f);
    bf16x8 bh2[4][2];                        // B frags from the swizzled LDS image
#pragma unroll
    for (int nt = 0; nt < 4; ++nt) {
      int wpx = w0w + nt*16 + l15;
#pragma unroll
      for (int kt = 0; kt < 2; ++kt)
        bh2[nt][kt] = *(const bf16x8*)(smem +
            ((wpx*128 + kt*64 + g*16) ^ ((wpx & 7) << 4)));
    }
    float s[4] = {0.0f, 0.0f, 0.0f, 0.0f};
#pragma unroll 2
    for (int mt = 0; mt < 8; ++mt) {
      const int arow = (mt*16 + l15)*64 + g*8;
      bf16x8 a0h = *(const bf16x8*)(Wu + FC1A_HI_U + arow);
      bf16x8 a0l = *(const bf16x8*)(Wu + FC1A_LO_U + arow);
      bf16x8 a1h = *(const bf16x8*)(Wu + FC1A_HI_U + arow + 32);
      bf16x8 a1l = *(const bf16x8*)(Wu + FC1A_LO_U + arow + 32);
      float f1b[4], f2v[4];
#pragma unroll
      for (int r = 0; r < 4; ++r) {
        f1b[r] = Wf[FC1B_F + mt*16 + g*4 + r];
        f2v[r] = Wf[FC2_F  + mt*16 + g*4 + r];
      }
#pragma unroll
      for (int nt = 0; nt < 4; ++nt) {
        f32x4 acc = {f1b[0], f1b[1], f1b[2], f1b[3]};
        acc = __builtin_amdgcn_mfma_f32_16x16x32_bf16(a0h, bh2[nt][0], acc, 0, 0, 0);
        acc = __builtin_amdgcn_mfma_f32_16x16x32_bf16(a0l, bh2[nt][0], acc, 0, 0, 0);
        acc = __builtin_amdgcn_mfma_f32_16x16x32_bf16(a1h, bh2[nt][1], acc, 0, 0, 0);
        acc = __builtin_amdgcn_mfma_f32_16x16x32_bf16(a1l, bh2[nt][1], acc, 0, 0, 0);
#pragma unroll
        for (int r = 0; r < 4; ++r)
          s[nt] += gelu10(acc[r]) * f2v[r];
      }
    }
    const float fc2b = Wf[FC2B_F];
#pragma unroll
    for (int nt = 0; nt < 4; ++nt) {
      float v = s[nt];
      v += __shfl_xor(v, 16);
      v += __shfl_xor(v, 32);
      if (g == 0) {
        size_t idx = (size_t)(b*256 + x)*256 + (w0w + nt*16 + l15);
        if (isf32) outF[idx] = v + fc2b;
        else       outH[idx] = __float2bfloat16(v + fc2b);
      }
    }
  }
}

// ---------------- launcher ----------------
extern "C" void kernel_launch(void* const* d_in, const int* in_sizes, int n_in,
                              void* d_out, int out_size, void* d_ws, size_t ws_size,
                              hipStream_t stream) {
  (void)out_size;
  __hip_bfloat16* outH = (__hip_bfloat16*)d_out;
  float*          outF = (float*)d_out;
  float*          Wf   = (float*)d_ws;
  __hip_bfloat16* HB   = (__hip_bfloat16*)d_ws + HB_OFF_U;
  __hip_bfloat16* GG   = (__hip_bfloat16*)d_ws + GG_OFF_U;
  float*          Fo   = (float*)d_ws + FO_OFF_F;

  static const int EXP_SZ[11] = {524288, 192, 64, 4718592, 4718592,
                                 16384, 256, 8192, 128, 128, 1};
  if (n_in != 11) { kf10_fill<<<2048, 256, 0, stream>>>(outH, 27648.0f); return; }
  for (int i = 0; i < 11; ++i) {
    if (in_sizes[i] != EXP_SZ[i]) {
      kf10_fill<<<2048, 256, 0, stream>>>(outH, 28672.0f + 256.0f * (float)i);
      return;
    }
  }
  if (ws_size < (size_t)WS_NEED) {
    int q = (int)(ws_size >> 25); if (q > 31) q = 31;
    kf10_fill<<<2048, 256, 0, stream>>>(outH, 4096.0f + 32.0f * (float)q);
    return;
  }

  kd10_detect<<<1, 64, 0, stream>>>((const unsigned short*)d_in[0], Wf);
  kt10_tables<<<64, 256, 0, stream>>>(
      (const __hip_bfloat16*)d_in[1], (const float*)d_in[1],
      (const __hip_bfloat16*)d_in[2], (const float*)d_in[2],
      (const __hip_bfloat16*)d_in[5], (const float*)d_in[5],
      (const __hip_bfloat16*)d_in[6], (const float*)d_in[6],
      (const __hip_bfloat16*)d_in[7], (const float*)d_in[7],
      (const __hip_bfloat16*)d_in[8], (const float*)d_in[8],
      (const __hip_bfloat16*)d_in[9], (const float*)d_in[9],
      (const __hip_bfloat16*)d_in[10], (const float*)d_in[10],
      Wf);
  kl11_lift<<<2048, 256, 0, stream>>>((const __hip_bfloat16*)d_in[0],
                                      (const float*)d_in[0], Wf, HB, GG);
  for (int l = 0; l < 4; ++l) {
    ks12_spec<<<192, 256, 0, stream>>>(Wf, GG,
        (const __hip_bfloat16*)d_in[3], (const float*)d_in[3],
        (const __hip_bfloat16*)d_in[4], (const float*)d_in[4],
        Fo, l);
    ky13_layer<<<2048, 256, 0, stream>>>(Wf, HB, GG, Fo, outH, outF,
                                         l, (l == 3) ? 1 : 0);
  }
}

// Round 11
// 687.791 us; speedup vs baseline: 1.3493x; 1.0033x over previous
//
#include <hip/hip_runtime.h>
#include <hip/hip_bf16.h>

// ---------------- workspace layout v20 (total 74,842,112 bytes) ----------------
// float indices into (float*)d_ws:
#define FC0_F   0        // fc0_w [64][3]
#define FC0B_F  192      // fc0_b [64]
#define PWB_F   16640    // pw_b [4][64]
#define FC1B_F  25088    // fc1_b [128]
#define FC2_F   25216    // fc2_w [128]
#define FC2B_F  25344    // fc2_b [1]
#define PHW_F   25408    // phW [256 w][12 ky][2] f32 (unused by kernels now; kept for layout)
#define PHH_F   31552    // phH [256 x][24 kx][2] f32 (spec + layer inv-H DFT)
#define FLAG_F  44032    // 1.0 => inputs f32
// u16 (bf16) element indices into (unsigned short*)d_ws:
#define PWA_HI_U 512     // pw [4][64 o][64 c] bf16 hi  (bytes 1024..33791)
#define PWA_LO_U 16896   // pw lo                       (bytes 33792..66559)
#define FC1A_HI_U 33792  // fc1 [128 f][64 c] bf16 hi (old f32 FC1T region)
#define FC1A_LO_U 41984  // fc1 lo (ends 50175 < 50176 = FC1B_F in u16)
#define TWI_HI_U 88192   // inv-W twiddle [256 w][32 k] hi (bytes 176384..192767)
#define TWI_LO_U 96384   // inv-W lo                       (bytes 192768..209151)
#define TWF_HI_U 104576  // fwd-W twiddle [32 r][256 w] hi (bytes 209152..225535)
#define TWF_LO_U 112768  // fwd-W lo                       (bytes 225536..241919)
// bf16 element indices into (__hip_bfloat16*)d_ws:
#define HB_OFF_U  131072     // h [8][256][256][64]  (33554432 elems)
#define GG_OFF_U  33685504   // G region: [8][256] rows x 1536 bf16
// float index for Fo:
#define FO_OFF_F  18415616   // Fo [8][12][24][64][2] f32 (294912)
#define WS_NEED   74842112
#define NT11 60161           // table items: same count as v12-v19

typedef short bf16x8 __attribute__((ext_vector_type(8)));   // 8 bf16 (4 VGPRs)
typedef float f32x4  __attribute__((ext_vector_type(4)));

union FU10 { float f; unsigned u; };
__device__ __forceinline__ float bfu2f(unsigned short u) { FU10 v; v.u = ((unsigned)u) << 16; return v.f; }
__device__ __forceinline__ unsigned short f2bfu(float f) {
  FU10 v; v.f = f; unsigned b = v.u;
  return (unsigned short)((b + 0x7FFFu + ((b >> 16) & 1u)) >> 16);   // RNE
}
__device__ __forceinline__ unsigned pk2bf(float a, float b) {
  return (unsigned)f2bfu(a) | ((unsigned)f2bfu(b) << 16);
}
// Branchless GELU: Abramowitz-Stegun 7.1.26 erf (max err 1.5e-7) + native rcp/exp.
__device__ __forceinline__ float gelu10(float v) {
  float s = v * 0.7071067811865475f;
  float a = fabsf(s);
  float t = __builtin_amdgcn_rcpf(1.0f + 0.3275911f * a);
  float p = t*(0.254829592f + t*(-0.284496736f + t*(1.421413741f
          + t*(-1.453152027f + t*1.061405429f))));
  float er = 1.0f - p * __expf(-a * a);
  er = copysignf(er, s);
  return 0.5f * v * (1.0f + er);
}
__device__ __forceinline__ float rdw10(const __hip_bfloat16* h, const float* f,
                                       long i, int isf32) {
  return isf32 ? f[i] : __bfloat162float(h[i]);
}
// g2T XOR swizzle: row o (64B rows), byte-in-row br; bijective, 16B-chunk aligned.
__device__ __forceinline__ int gsw17(int o, int br) {
  return (o*64 + br) ^ ((o & 7) << 4);
}

// ---------------- fill output with a code (guards only) ----------------
__global__ __launch_bounds__(256) void kf10_fill(__hip_bfloat16* outH, float code) {
  outH[(size_t)blockIdx.x * 256 + threadIdx.x] = __float2bfloat16(code);
}

// ---------------- dtype detect on X ----------------
__global__ __launch_bounds__(64) void kd10_detect(const unsigned short* Xh, float* Wf) {
  if (threadIdx.x == 0 && blockIdx.x == 0) {
    int ok = 1;
    for (int k = 0; k < 128; ++k) {
      unsigned short u = Xh[2 * k];
      unsigned e = (u >> 7) & 0xFF;
      if (!(u == 0 || (e >= 0x60 && e <= 0x88))) ok = 0;
    }
    Wf[FLAG_F] = ok ? 0.0f : 1.0f;
  }
}

// ---------------- tables ----------------
__global__ __launch_bounds__(256) void kt10_tables(
    const __hip_bfloat16* f0h, const float* f0f,
    const __hip_bfloat16* f0bh, const float* f0bf,
    const __hip_bfloat16* pwh, const float* pwf,
    const __hip_bfloat16* pwbh, const float* pwbf,
    const __hip_bfloat16* f1h, const float* f1f,
    const __hip_bfloat16* f1bh, const float* f1bf,
    const __hip_bfloat16* f2h, const float* f2f,
    const __hip_bfloat16* f2bh, const float* f2bf,
    float* Wf) {
  unsigned short* Wu = (unsigned short*)Wf;
  const int isf32 = (Wf[FLAG_F] != 0.0f);
  const int stride = gridDim.x * blockDim.x;
  for (int n0 = blockIdx.x * blockDim.x + threadIdx.x; n0 < NT11; n0 += stride) {
    int n = n0;
    if (n < 192) { Wf[FC0_F + n] = rdw10(f0h, f0f, n, isf32); continue; }
    n -= 192;
    if (n < 64)  { Wf[FC0B_F + n] = rdw10(f0bh, f0bf, n, isf32); continue; }
    n -= 64;
    if (n < 256) { Wf[PWB_F + n] = rdw10(pwbh, pwbf, n, isf32); continue; }
    n -= 256;
    if (n < 8192) {             // fc1 split bf16, natural [f][c] layout
      float v = rdw10(f1h, f1f, n, isf32);
      unsigned short hi = f2bfu(v);
      Wu[FC1A_HI_U + n] = hi;
      Wu[FC1A_LO_U + n] = f2bfu(v - bfu2f(hi));
      continue;
    }
    n -= 8192;
    if (n < 128) { Wf[FC1B_F + n] = rdw10(f1bh, f1bf, n, isf32); continue; }
    n -= 128;
    if (n < 128) { Wf[FC2_F + n] = rdw10(f2h, f2f, n, isf32); continue; }
    n -= 128;
    if (n < 1)   { Wf[FC2B_F + n] = rdw10(f2bh, f2bf, 0, isf32); continue; }
    n -= 1;
    if (n < 6144) { int w = n / 24, r = n % 24, ky = r >> 1, part = r & 1;
      int idx = (w * ky) & 255; float a = idx * (1.0f/128.0f);
      Wf[PHW_F + n] = part ? sinpif(a) : cospif(a); continue; }
    n -= 6144;
    if (n < 12288) { int xx = n / 48, r = n % 48, kx = r >> 1, part = r & 1;
      int kxa = (kx < 12) ? kx : kx + 232;          // 244..255 = negative H rows
      int idx = (xx * kxa) & 255; float a = idx * (1.0f/128.0f);
      Wf[PHH_F + n] = part ? sinpif(a) : cospif(a); continue; }
    n -= 12288;
    if (n < 16384) {            // pw split bf16, [l][o][c] == input linear layout
      float v = rdw10(pwh, pwf, n, isf32);
      unsigned short hi = f2bfu(v);
      Wu[PWA_HI_U + n] = hi;
      Wu[PWA_LO_U + n] = f2bfu(v - bfu2f(hi));
      continue;
    }
    n -= 16384;
    if (n < 8192) {             // inv-W twiddle [256 w][32 k], scale 1/65536 folded in
      int w = n >> 5, k = n & 31;
      float v;
      if (k == 0)      v = 1.0f / 65536.0f;
      else if (k < 12) { int idx = (w*k) & 255;
        v =  2.0f * cospif(idx * (1.0f/128.0f)) * (1.0f/65536.0f); }
      else if (k < 23) { int ky = k - 11; int idx = (w*ky) & 255;
        v = -2.0f * sinpif(idx * (1.0f/128.0f)) * (1.0f/65536.0f); }
      else v = 0.0f;
      unsigned short hi = f2bfu(v);
      Wu[TWI_HI_U + n] = hi;
      Wu[TWI_LO_U + n] = f2bfu(v - bfu2f(hi));
      continue;
    }
    n -= 8192;
    {                           // fwd-W twiddle [32 r][256 w]: r<12 cos, 12..23 -sin, rest 0
      int r = n >> 8, w = n & 255;
      float v;
      if (r < 12)      { int idx = (w*r) & 255;  v =  cospif(idx * (1.0f/128.0f)); }
      else if (r < 24) { int ky = r - 12; int idx = (w*ky) & 255;
                         v = -sinpif(idx * (1.0f/128.0f)); }
      else v = 0.0f;
      unsigned short hi = f2bfu(v);
      Wu[TWF_HI_U + n] = hi;
      Wu[TWF_LO_U + n] = f2bfu(v - bfu2f(hi));
    }
  }
}

// ---------------- lift: fc0 in registers -> HB + swizzled LDS image ->
//                  MFMA fwd DFT-W -> GG ------------------------------------------
__global__ __launch_bounds__(256) void kl11_lift(const __hip_bfloat16* Xh, const float* Xf,
                                                 const float* Wf,
                                                 __hip_bfloat16* HB, __hip_bfloat16* GG) {
  __shared__ __align__(16) char smem[32768];
  unsigned short* gbT = (unsigned short*)smem;   // phase-2 staging (aliases image)
  const unsigned short* Wu = (const unsigned short*)Wf;
  const int rid = ((blockIdx.x & 7) << 8) | (blockIdx.x >> 3);
  const int b = rid >> 8, x = rid & 255;
  const int t = threadIdx.x;
  const int w = t;                               // this thread's pixel
  const int l15 = t & 15, g = (t >> 4) & 3, wv = t >> 6;
  const int isf32 = (Wf[FLAG_F] != 0.0f);
  float xv = isf32 ? Xf[(size_t)(b*256 + x)*256 + w]
                   : __bfloat162float(Xh[(size_t)(b*256 + x)*256 + w]);
  float gx = x * (1.0f/255.0f), gy = w * (1.0f/255.0f);
  unsigned hbreg[32];
#pragma unroll
  for (int cp = 0; cp < 32; ++cp) {
    int c = cp*2;
    float h0 = xv*Wf[FC0_F + c*3]     + gx*Wf[FC0_F + c*3 + 1]
             + gy*Wf[FC0_F + c*3 + 2] + Wf[FC0B_F + c];
    float h1 = xv*Wf[FC0_F + c*3 + 3] + gx*Wf[FC0_F + c*3 + 4]
             + gy*Wf[FC0_F + c*3 + 5] + Wf[FC0B_F + c + 1];
    unsigned pk = pk2bf(h0, h1);
    hbreg[cp] = pk;
    // channel-major swizzled image for the MFMA fwd-DFT A-side
    *(unsigned short*)(smem + (((c+0)*512 + w*2) ^ (((c+0) & 7) << 4))) =
        (unsigned short)(pk & 0xFFFFu);
    *(unsigned short*)(smem + (((c+1)*512 + w*2) ^ (((c+1) & 7) << 4))) =
        (unsigned short)(pk >> 16);
  }
  // HB store: this lane fully covers its own 128 B pixel line
  {
    uint4* hbW = (uint4*)(HB + (size_t)(b*256 + x)*16384) + w*8;
#pragma unroll
    for (int j = 0; j < 8; ++j)
      hbW[j] = make_uint4(hbreg[j*4], hbreg[j*4+1], hbreg[j*4+2], hbreg[j*4+3]);
  }
  __syncthreads();                               // image complete

  // ---- MFMA fwd DFT-W: G[c][r] = sum_w h[w][c] * TwFwd[r][w] ----
  f32x4 g0 = {0.f, 0.f, 0.f, 0.f}, g1 = {0.f, 0.f, 0.f, 0.f};
  const int crow = wv*16 + l15;                  // A row (channel)
  const int rswz = (crow & 7) << 4;
#pragma unroll
  for (int kk = 0; kk < 8; ++kk) {
    const int k0 = kk*32;
    bf16x8 af  = *(const bf16x8*)(smem + ((crow*512 + (k0 + g*8)*2) ^ rswz));
    bf16x8 b0h = *(const bf16x8*)(Wu + TWF_HI_U + l15*256 + k0 + g*8);
    bf16x8 b0l = *(const bf16x8*)(Wu + TWF_LO_U + l15*256 + k0 + g*8);
    bf16x8 b1h = *(const bf16x8*)(Wu + TWF_HI_U + (16 + l15)*256 + k0 + g*8);
    bf16x8 b1l = *(const bf16x8*)(Wu + TWF_LO_U + (16 + l15)*256 + k0 + g*8);
    g0 = __builtin_amdgcn_mfma_f32_16x16x32_bf16(af, b0h, g0, 0, 0, 0);
    g0 = __builtin_amdgcn_mfma_f32_16x16x32_bf16(af, b0l, g0, 0, 0, 0);
    g1 = __builtin_amdgcn_mfma_f32_16x16x32_bf16(af, b1h, g1, 0, 0, 0);
    g1 = __builtin_amdgcn_mfma_f32_16x16x32_bf16(af, b1l, g1, 0, 0, 0);
  }
  __syncthreads();                               // image reads done; staging may overwrite
#pragma unroll
  for (int ntk = 0; ntk < 2; ++ntk) {
    int kyt = ntk*16 + l15;                      // C col = ky term
    if (kyt < 24) {
      f32x4 gg = ntk ? g1 : g0;
#pragma unroll
      for (int rr = 0; rr < 4; ++rr)
        gbT[(wv*16 + g*4 + rr)*24 + kyt] = f2bfu(gg[rr]);
    }
  }
  __syncthreads();                               // staging complete
  unsigned* GGrow = (unsigned*)((unsigned short*)GG + (size_t)(b*256 + x)*1536);
  const unsigned* st32 = (const unsigned*)gbT;
#pragma unroll
  for (int j = 0; j < 3; ++j) GGrow[j*256 + t] = st32[j*256 + t];
}

// ---------------- spectral: 256-thread (round-6 A/B winner) ---------------------
// Block=(b,kx), XCD swizzle b = blockIdx&7.
__global__ __launch_bounds__(256) void ks12_spec(const float* Wf, const __hip_bfloat16* GG,
    const __hip_bfloat16* w1h, const float* w1f,
    const __hip_bfloat16* w2h, const float* w2f,
    float* Fo, int l) {
  __shared__ float pbufA[6400];
  __shared__ float Fbuf[1536];     // F [i][24]: m<12 re[ky], m>=12 im[ky]
  const int blk = (blockIdx.x & 7) * 24 + (blockIdx.x >> 3);
  const int b = blk / 24, kx = blk % 24;
  const int t = threadIdx.x;
  const int isf32 = (Wf[FLAG_F] != 0.0f);
  // A: F[i][ky] = sum_x G[b][x][i][ky] * e^{-i 2pi x kxa/256}
  {
    const int i = t & 63, q = t >> 6;
    float fr[12], fi[12];
#pragma unroll
    for (int k = 0; k < 12; ++k) { fr[k] = 0.0f; fi[k] = 0.0f; }
    for (int j = 0; j < 64; ++j) {
      int x = q*64 + j;                          // wave-uniform
      const uint4* gp = (const uint4*)((const unsigned short*)GG
                        + (size_t)(b*256 + x)*1536 + i*24);
      uint4 u0 = gp[0], u1 = gp[1], u2 = gp[2];
      float cc = Wf[PHH_F + x*48 + 2*kx], sn = Wf[PHH_F + x*48 + 2*kx + 1];
      unsigned uu[12] = {u0.x, u0.y, u0.z, u0.w, u1.x, u1.y, u1.z, u1.w,
                         u2.x, u2.y, u2.z, u2.w};
      // G layout: elems 0..11 = re[k], 12..23 = im[k]
#pragma unroll
      for (int k = 0; k < 12; ++k) {
        unsigned ure = uu[k >> 1], uim = uu[6 + (k >> 1)];
        float gr = bfu2f((unsigned short)((k & 1) ? (ure >> 16) : (ure & 0xFFFFu)));
        float gi = bfu2f((unsigned short)((k & 1) ? (uim >> 16) : (uim & 0xFFFFu)));
        fr[k] += gr*cc + gi*sn;
        fi[k] += gi*cc - gr*sn;
      }
    }
#pragma unroll
    for (int k = 0; k < 12; ++k) {
      pbufA[q*1600 + i*25 + 2*k]     = fr[k];
      pbufA[q*1600 + i*25 + 2*k + 1] = fi[k];
    }
  }
  __syncthreads();
#pragma unroll
  for (int j = 0; j < 6; ++j) {
    int idx = j*256 + t;                         // 1536 = i*24 + m
    int cc = idx / 24, m = idx - cc*24;
    Fbuf[idx] = pbufA[cc*25 + m] + pbufA[1600 + cc*25 + m]
              + pbufA[3200 + cc*25 + m] + pbufA[4800 + cc*25 + m];
  }
  __syncthreads();
  // B: Fo[ky][o] = sum_i F[i][ky] * W[l][i][o][kx][ky]
  {
    const int o = t & 63, q = t >> 6;
    float br[12], bi[12];
#pragma unroll
    for (int k = 0; k < 12; ++k) { br[k] = 0.0f; bi[k] = 0.0f; }
    const int kxe = (kx < 12) ? kx : kx - 12;
    const __hip_bfloat16* wh = (kx < 12) ? w1h : w2h;
    const float*         wfp = (kx < 12) ? w1f : w2f;
    for (int i = q*16; i < q*16 + 16; ++i) {
      size_t widx = ((size_t)((l*64 + i)*64 + o))*288 + (size_t)kxe*24;
      float wr_[12], wi_[12];
      if (isf32) {
        const float* wp = wfp + widx;
#pragma unroll
        for (int k = 0; k < 12; ++k) { wr_[k] = wp[2*k]; wi_[k] = wp[2*k + 1]; }
      } else {
        const uint4* wp = (const uint4*)((const unsigned short*)wh + widx);
        uint4 u0 = wp[0], u1 = wp[1], u2 = wp[2];
        unsigned uu[12] = {u0.x, u0.y, u0.z, u0.w, u1.x, u1.y, u1.z, u1.w,
                           u2.x, u2.y, u2.z, u2.w};
#pragma unroll
        for (int k = 0; k < 12; ++k) {
          wr_[k] = bfu2f((unsigned short)(uu[k] & 0xFFFFu));
          wi_[k] = bfu2f((unsigned short)(uu[k] >> 16));
        }
      }
      const float* Fp = Fbuf + i*24;
#pragma unroll
      for (int k = 0; k < 12; ++k) {
        float Fr = Fp[k], Fi = Fp[12 + k];
        br[k] += Fr*wr_[k] - Fi*wi_[k];
        bi[k] += Fr*wi_[k] + Fi*wr_[k];
      }
    }
#pragma unroll
    for (int k = 0; k < 12; ++k) {
      pbufA[q*1536 + k*128 + o*2]     = br[k];
      pbufA[q*1536 + k*128 + o*2 + 1] = bi[k];
    }
  }
  __syncthreads();
#pragma unroll
  for (int j = 0; j < 6; ++j) {
    int n = j*256 + t;                           // 1536 = ky*128 + o*2 + p
    int ky = n >> 7, r = n & 127;
    Fo[((size_t)(b*12 + ky)*24 + kx)*128 + r] =
        pbufA[n] + pbufA[1536 + n] + pbufA[3072 + n] + pbufA[4608 + n];
  }
}

// ---------------- layer v20: identical to v19 EXCEPT phase 0's j-loop is no
//                  longer pinned to unroll 1 — the compiler may software-pipeline
//                  the 72 strided Fo loads across rounds (G7). ------------------
__global__ __launch_bounds__(256) void ky15_layer(const float* __restrict__ Wf,
                                                  __hip_bfloat16* __restrict__ HB,
                                                  __hip_bfloat16* __restrict__ GG,
                                                  const float* __restrict__ Fo,
                                                  __hip_bfloat16* __restrict__ outH,
                                                  float* __restrict__ outF,
                                                  int l, int last) {
  __shared__ __align__(16) char smem[32768];
  unsigned short* gbT = (unsigned short*)smem;   // staging [64][24] for phase 2 only
  const unsigned short* Wu = (const unsigned short*)Wf;
  const int rid = ((blockIdx.x & 7) << 8) | (blockIdx.x >> 3);
  const int b = rid >> 8, x = rid & 255;
  const int t = threadIdx.x;
  const int l15 = t & 15, g = (t >> 4) & 3, wv = t >> 6;

  unsigned short* HBu = (unsigned short*)(HB + (size_t)(b*256 + x)*16384);
  unsigned short* GGu = (unsigned short*)GG + (size_t)(b*256 + x)*1536;

  // ---- issue h_old global loads first (longest latency) ----
  const int w0w = wv*64;                     // wave owns pixels [w0w, w0w+64)
  bf16x8 bh[4][2];                           // pointwise B: h_old frags from HB global
#pragma unroll
  for (int nt = 0; nt < 4; ++nt) {
    int wpx = w0w + nt*16 + l15;
#pragma unroll
    for (int kt = 0; kt < 2; ++kt)
      bh[nt][kt] = *(const bf16x8*)(HBu + (size_t)wpx*64 + kt*32 + g*8);
  }

  // ---- phase 0: inline inverse-H DFT: Fo -> g2T (XOR-swizzled) in LDS ----
  { int o = t >> 2, cu = t & 3;              // zero cols 24-31 (bytes 48..63 of row)
    *(unsigned*)(smem + gsw17(o, 48 + cu*4)) = 0u; }
  {
    const float* phx = Wf + PHH_F + x*48;    // block-uniform twiddles
    for (int j = 0; j < 3; ++j) {            // compiler may pipeline/unroll (v20)
      int p = j*256 + t; int ky = p >> 6, o = p & 63;
      const float2* Fop = (const float2*)(Fo + (size_t)(b*12 + ky)*3072) + o;
      float gr = 0.0f, gi = 0.0f;
#pragma unroll
      for (int kx = 0; kx < 24; ++kx) {
        float2 f = Fop[kx*64];
        float cc = phx[2*kx], sn = phx[2*kx + 1];
        gr += f.x*cc - f.y*sn;
        gi += f.x*sn + f.y*cc;
      }
      *(unsigned short*)(smem + gsw17(o, ky*2)) = f2bfu(gr);             // re -> col ky
      *(unsigned short*)(smem + gsw17(o, (ky ? (11 + ky) : 23)*2)) = f2bfu(gi);
    }
  }

  // ---- weight fragment loads (L2-hot) ----
  bf16x8 bi[4][2];                           // inv-DFT B: twiddle hi/lo
#pragma unroll
  for (int nt = 0; nt < 4; ++nt) {
    int wpx = w0w + nt*16 + l15;
    bi[nt][0] = *(const bf16x8*)(Wu + TWI_HI_U + wpx*32 + g*8);
    bi[nt][1] = *(const bf16x8*)(Wu + TWI_LO_U + wpx*32 + g*8);
  }
  bf16x8 apw[4][2][2];                       // pointwise A: pw[o][c] hi/lo
#pragma unroll
  for (int mt = 0; mt < 4; ++mt)
#pragma unroll
    for (int kt = 0; kt < 2; ++kt) {
      int off = l*4096 + (mt*16 + l15)*64 + kt*32 + g*8;
      apw[mt][kt][0] = *(const bf16x8*)(Wu + PWA_HI_U + off);
      apw[mt][kt][1] = *(const bf16x8*)(Wu + PWA_LO_U + off);
    }
  float bias[4][4];
#pragma unroll
  for (int mt = 0; mt < 4; ++mt)
#pragma unroll
    for (int r = 0; r < 4; ++r)
      bias[mt][r] = Wf[PWB_F + l*64 + mt*16 + g*4 + r];

  __syncthreads();                           // g2T complete
  bf16x8 ainv[4];                            // inv-DFT A: g2T frags (swizzled read)
#pragma unroll
  for (int mt = 0; mt < 4; ++mt)
    ainv[mt] = *(const bf16x8*)(smem + gsw17(mt*16 + l15, g*16));
  __syncthreads();                           // frag reads done; image may overwrite

  // ---- phase 1: 16 C-tiles per wave; epilogue -> HB + swizzled LDS image ----
  // !last: image is [c][w] (channel-major) for the fwd-DFT A-side.
  //  last: image is [w][c] (pixel-major)   for the head's B-side; HB write skipped.
#pragma unroll
  for (int nt = 0; nt < 4; ++nt) {
    const int wpx = w0w + nt*16 + l15;       // C col (pixel) for this lane
#pragma unroll
    for (int mt = 0; mt < 4; ++mt) {
      f32x4 acc = {bias[mt][0], bias[mt][1], bias[mt][2], bias[mt][3]};
      acc = __builtin_amdgcn_mfma_f32_16x16x32_bf16(ainv[mt],      bi[nt][0], acc, 0, 0, 0);
      acc = __builtin_amdgcn_mfma_f32_16x16x32_bf16(ainv[mt],      bi[nt][1], acc, 0, 0, 0);
      acc = __builtin_amdgcn_mfma_f32_16x16x32_bf16(apw[mt][0][0], bh[nt][0], acc, 0, 0, 0);
      acc = __builtin_amdgcn_mfma_f32_16x16x32_bf16(apw[mt][0][1], bh[nt][0], acc, 0, 0, 0);
      acc = __builtin_amdgcn_mfma_f32_16x16x32_bf16(apw[mt][1][0], bh[nt][1], acc, 0, 0, 0);
      acc = __builtin_amdgcn_mfma_f32_16x16x32_bf16(apw[mt][1][1], bh[nt][1], acc, 0, 0, 0);
      float v0 = acc[0], v1 = acc[1], v2 = acc[2], v3 = acc[3];
      if (!last) { v0 = gelu10(v0); v1 = gelu10(v1); v2 = gelu10(v2); v3 = gelu10(v3); }
      const int c0 = mt*16 + g*4;            // C rows = channels c0..c0+3
      uint2 pk; pk.x = pk2bf(v0, v1); pk.y = pk2bf(v2, v3);
      if (!last) {
        *(uint2*)(HBu + (size_t)wpx*64 + c0) = pk;
        // h_new^T image for fwd-DFT, XOR-swizzled
        *(unsigned short*)(smem + (((c0+0)*512 + wpx*2) ^ (((c0+0) & 7) << 4))) = f2bfu(v0);
        *(unsigned short*)(smem + (((c0+1)*512 + wpx*2) ^ (((c0+1) & 7) << 4))) = f2bfu(v1);
        *(unsigned short*)(smem + (((c0+2)*512 + wpx*2) ^ (((c0+2) & 7) << 4))) = f2bfu(v2);
        *(unsigned short*)(smem + (((c0+3)*512 + wpx*2) ^ (((c0+3) & 7) << 4))) = f2bfu(v3);
      } else {
        // pixel-major h image for head B-frags, XOR-swizzled on pixel
        *(uint2*)(smem + ((wpx*128 + c0*2) ^ ((wpx & 7) << 4))) = pk;
      }
    }
  }

  if (!last) {
    // ---- phase 2: fwd DFT-W: G[c][r] = sum_w h_new[w][c] * TwFwd[r][w] ----
    __syncthreads();                         // h_new image complete
    f32x4 g0 = {0.f, 0.f, 0.f, 0.f}, g1 = {0.f, 0.f, 0.f, 0.f};
    const int crow = wv*16 + l15;            // A row (channel); wave owns c-slab wv*16..+16
    const int rswz = (crow & 7) << 4;
#pragma unroll
    for (int kk = 0; kk < 8; ++kk) {
      const int k0 = kk*32;
      bf16x8 af  = *(const bf16x8*)(smem + ((crow*512 + (k0 + g*8)*2) ^ rswz));
      bf16x8 b0h = *(const bf16x8*)(Wu + TWF_HI_U + l15*256 + k0 + g*8);
      bf16x8 b0l = *(const bf16x8*)(Wu + TWF_LO_U + l15*256 + k0 + g*8);
      bf16x8 b1h = *(const bf16x8*)(Wu + TWF_HI_U + (16 + l15)*256 + k0 + g*8);
      bf16x8 b1l = *(const bf16x8*)(Wu + TWF_LO_U + (16 + l15)*256 + k0 + g*8);
      g0 = __builtin_amdgcn_mfma_f32_16x16x32_bf16(af, b0h, g0, 0, 0, 0);
      g0 = __builtin_amdgcn_mfma_f32_16x16x32_bf16(af, b0l, g0, 0, 0, 0);
      g1 = __builtin_amdgcn_mfma_f32_16x16x32_bf16(af, b1h, g1, 0, 0, 0);
      g1 = __builtin_amdgcn_mfma_f32_16x16x32_bf16(af, b1l, g1, 0, 0, 0);
    }
    __syncthreads();                         // image reads done; staging may overwrite
    // stage [64 c][24 r] bf16 into gbT (linear layout), then coalesced GG store
#pragma unroll
    for (int ntk = 0; ntk < 2; ++ntk) {
      int kyt = ntk*16 + l15;                // C col = kyterm
      if (kyt < 24) {
        f32x4 gg = ntk ? g1 : g0;
#pragma unroll
        for (int rr = 0; rr < 4; ++rr)
          gbT[(wv*16 + g*4 + rr)*24 + kyt] = f2bfu(gg[rr]);
      }
    }
    __syncthreads();                         // staging complete
    unsigned* GGrow = (unsigned*)GGu;
    const unsigned* st32 = (const unsigned*)gbT;
#pragma unroll
    for (int j = 0; j < 3; ++j) GGrow[j*256 + t] = st32[j*256 + t];
  } else {
    // ---- phase 2': fused head: fc1 (hi/lo MFMA) + GELU + fc2 reduce -> out ----
    __syncthreads();                         // h image complete
    const int isf32 = (Wf[FLAG_F] != 0.0f);
    bf16x8 bh2[4][2];                        // B frags from the swizzled LDS image
#pragma unroll
    for (int nt = 0; nt < 4; ++nt) {
      int wpx = w0w + nt*16 + l15;
#pragma unroll
      for (int kt = 0; kt < 2; ++kt)
        bh2[nt][kt] = *(const bf16x8*)(smem +
            ((wpx*128 + kt*64 + g*16) ^ ((wpx & 7) << 4)));
    }
    float s[4] = {0.0f, 0.0f, 0.0f, 0.0f};
#pragma unroll 2
    for (int mt = 0; mt < 8; ++mt) {
      const int arow = (mt*16 + l15)*64 + g*8;
      bf16x8 a0h = *(const bf16x8*)(Wu + FC1A_HI_U + arow);
      bf16x8 a0l = *(const bf16x8*)(Wu + FC1A_LO_U + arow);
      bf16x8 a1h = *(const bf16x8*)(Wu + FC1A_HI_U + arow + 32);
      bf16x8 a1l = *(const bf16x8*)(Wu + FC1A_LO_U + arow + 32);
      float f1b[4], f2v[4];
#pragma unroll
      for (int r = 0; r < 4; ++r) {
        f1b[r] = Wf[FC1B_F + mt*16 + g*4 + r];
        f2v[r] = Wf[FC2_F  + mt*16 + g*4 + r];
      }
#pragma unroll
      for (int nt = 0; nt < 4; ++nt) {
        f32x4 acc = {f1b[0], f1b[1], f1b[2], f1b[3]};
        acc = __builtin_amdgcn_mfma_f32_16x16x32_bf16(a0h, bh2[nt][0], acc, 0, 0, 0);
        acc = __builtin_amdgcn_mfma_f32_16x16x32_bf16(a0l, bh2[nt][0], acc, 0, 0, 0);
        acc = __builtin_amdgcn_mfma_f32_16x16x32_bf16(a1h, bh2[nt][1], acc, 0, 0, 0);
        acc = __builtin_amdgcn_mfma_f32_16x16x32_bf16(a1l, bh2[nt][1], acc, 0, 0, 0);
#pragma unroll
        for (int r = 0; r < 4; ++r)
          s[nt] += gelu10(acc[r]) * f2v[r];
      }
    }
    const float fc2b = Wf[FC2B_F];
#pragma unroll
    for (int nt = 0; nt < 4; ++nt) {
      float v = s[nt];
      v += __shfl_xor(v, 16);
      v += __shfl_xor(v, 32);
      if (g == 0) {
        size_t idx = (size_t)(b*256 + x)*256 + (w0w + nt*16 + l15);
        if (isf32) outF[idx] = v + fc2b;
        else       outH[idx] = __float2bfloat16(v + fc2b);
      }
    }
  }
}

// ---------------- launcher ----------------
extern "C" void kernel_launch(void* const* d_in, const int* in_sizes, int n_in,
                              void* d_out, int out_size, void* d_ws, size_t ws_size,
                              hipStream_t stream) {
  (void)out_size;
  __hip_bfloat16* outH = (__hip_bfloat16*)d_out;
  float*          outF = (float*)d_out;
  float*          Wf   = (float*)d_ws;
  __hip_bfloat16* HB   = (__hip_bfloat16*)d_ws + HB_OFF_U;
  __hip_bfloat16* GG   = (__hip_bfloat16*)d_ws + GG_OFF_U;
  float*          Fo   = (float*)d_ws + FO_OFF_F;

  static const int EXP_SZ[11] = {524288, 192, 64, 4718592, 4718592,
                                 16384, 256, 8192, 128, 128, 1};
  if (n_in != 11) { kf10_fill<<<2048, 256, 0, stream>>>(outH, 27648.0f); return; }
  for (int i = 0; i < 11; ++i) {
    if (in_sizes[i] != EXP_SZ[i]) {
      kf10_fill<<<2048, 256, 0, stream>>>(outH, 28672.0f + 256.0f * (float)i);
      return;
    }
  }
  if (ws_size < (size_t)WS_NEED) {
    int q = (int)(ws_size >> 25); if (q > 31) q = 31;
    kf10_fill<<<2048, 256, 0, stream>>>(outH, 4096.0f + 32.0f * (float)q);
    return;
  }

  kd10_detect<<<1, 64, 0, stream>>>((const unsigned short*)d_in[0], Wf);
  kt10_tables<<<64, 256, 0, stream>>>(
      (const __hip_bfloat16*)d_in[1], (const float*)d_in[1],
      (const __hip_bfloat16*)d_in[2], (const float*)d_in[2],
      (const __hip_bfloat16*)d_in[5], (const float*)d_in[5],
      (const __hip_bfloat16*)d_in[6], (const float*)d_in[6],
      (const __hip_bfloat16*)d_in[7], (const float*)d_in[7],
      (const __hip_bfloat16*)d_in[8], (const float*)d_in[8],
      (const __hip_bfloat16*)d_in[9], (const float*)d_in[9],
      (const __hip_bfloat16*)d_in[10], (const float*)d_in[10],
      Wf);
  kl11_lift<<<2048, 256, 0, stream>>>((const __hip_bfloat16*)d_in[0],
                                      (const float*)d_in[0], Wf, HB, GG);
  for (int l = 0; l < 4; ++l) {
    ks12_spec<<<192, 256, 0, stream>>>(Wf, GG,
        (const __hip_bfloat16*)d_in[3], (const float*)d_in[3],
        (const __hip_bfloat16*)d_in[4], (const float*)d_in[4],
        Fo, l);
    ky15_layer<<<2048, 256, 0, stream>>>(Wf, HB, GG, Fo, outH, outF,
                                         l, (l == 3) ? 1 : 0);
  }
}